// Round 1
// baseline (186.779 us; speedup 1.0000x reference)
//
#include <hip/hip_runtime.h>

// Problem constants (hardcoded from reference):
//   T=4096, D_MODEL=1024, N_HEADS=16, HEAD_DIM=64, ROT=32, PAIR=16,
//   EPS=1e-6, SCALE=0.12, WINDOW=1024. tokens/pos/block_size unused.
//
// Attention numerics: rmsnorm => ||q||=||k||=8, so |q.k|*SCALE <= 7.68 ->
// exp bounded [4.6e-4, 2164]: softmax max-subtraction unnecessary.
// SCALE*log2(e) pre-folded into Q at the gemm_qkv epilogue: p = exp2(z).
//
// Composition (R5-R11 evidence + this round):
//  - attn: R8-exact. K AND V staged in LDS, 4-wave blocks, single-buffer.
//  - gemm_qkv: R9. BM64/BK64 single-buffer, 6 blocks/CU.
//  - gemm_out: THIS ROUND — 64x64 tiles, 1024 blocks (4/CU, 16 waves/CU),
//    XCD-chunked remap (A-panel 1MB + B 2MB L2-resident per XCD),
//    prefetch-dbuf kept. Fixes the 2-blocks/CU supply starvation the prior
//    session identified but did not resolve.

typedef __bf16 bf16x8 __attribute__((ext_vector_type(8)));
typedef __bf16 bf16x2 __attribute__((ext_vector_type(2)));
typedef float f32x4 __attribute__((ext_vector_type(4)));
typedef unsigned short u16x8 __attribute__((ext_vector_type(8)));
typedef unsigned short u16x4 __attribute__((ext_vector_type(4)));

#define MFMA16(a, b, c) __builtin_amdgcn_mfma_f32_16x16x32_bf16((a), (b), (c), 0, 0, 0)

__device__ __forceinline__ unsigned short f2bf(float f) {
    unsigned int u = __float_as_uint(f);
    u += 0x7fffu + ((u >> 16) & 1u);   // round-to-nearest-even
    return (unsigned short)(u >> 16);
}
__device__ __forceinline__ float bf2f(unsigned short h) {
    return __uint_as_float(((unsigned int)h) << 16);
}
__device__ __forceinline__ unsigned int pk2bf(float a, float b) {
#if __has_builtin(__builtin_amdgcn_cvt_pk_bf16_f32)
    bf16x2 v = __builtin_amdgcn_cvt_pk_bf16_f32(a, b);
    return __builtin_bit_cast(unsigned int, v);
#else
    return (unsigned int)f2bf(a) | ((unsigned int)f2bf(b) << 16);
#endif
}
__device__ __forceinline__ float fexp2(float x) {
#if __has_builtin(__builtin_amdgcn_exp2f)
    return __builtin_amdgcn_exp2f(x);   // raw v_exp_f32; args bounded +-1.33
#else
    return exp2f(x);
#endif
}

// async global->LDS, 16B per lane; LDS dest = wave-uniform base + lane*16
__device__ __forceinline__ void gl_lds16(const void* g, void* l) {
    typedef __attribute__((address_space(1))) unsigned int GU;
    typedef __attribute__((address_space(3))) unsigned int LU;
    __builtin_amdgcn_global_load_lds((GU*)(unsigned long long)g,
                                     (LU*)(unsigned int)(unsigned long long)l,
                                     16, 0, 0);
}

// ---------------- K0: fused fp32 -> bf16 convert (x, w_qkv, w_o) ----------
__global__ void cvt3_kernel(const float* __restrict__ x,
                            const float* __restrict__ wqkv,
                            const float* __restrict__ wo,
                            unsigned short* __restrict__ xb,
                            unsigned short* __restrict__ wqkvb,
                            unsigned short* __restrict__ wob) {
    int i = blockIdx.x * 256 + threadIdx.x;
    const float* src;
    unsigned short* dst;
    int off;
    if (i < 1048576) { src = x; dst = xb; off = i; }
    else if (i < 1835008) { src = wqkv; dst = wqkvb; off = i - 1048576; }
    else { src = wo; dst = wob; off = i - 1835008; }
    float4 f = ((const float4*)src)[off];
    u16x4 o;
    o[0] = f2bf(f.x); o[1] = f2bf(f.y); o[2] = f2bf(f.z); o[3] = f2bf(f.w);
    ((u16x4*)dst)[off] = o;
}

// ---------------- K1: qkv GEMM + fused rmsnorm/rope/pack epilogue ----------
// (R9 config: 64x128xBK64 single-buffer, 6/CU, aliased epilogue LDS)
#define TBS 72
__global__ __launch_bounds__(256, 6) void gemm_qkv(
    const unsigned short* __restrict__ A,    // xb [4096][1024]
    const unsigned short* __restrict__ Bt,   // wqkvb [3072][1024]
    const float* __restrict__ cosb, const float* __restrict__ sinb,  // [T][16]
    const float* __restrict__ qw, const float* __restrict__ kw,      // [64]
    unsigned short* __restrict__ Qb,  // [H][T][64] (pre-scaled)
    unsigned short* __restrict__ Kb,  // [H][T][64]
    unsigned short* __restrict__ Vt)  // [H][64][T] (pre-scaled by 0.5)
{
    __shared__ unsigned short smem[12288];  // 24 KB
    unsigned short* As0 = smem;
    unsigned short* As1 = smem + 2048;
    unsigned short* Bs0 = smem + 4096;
    unsigned short* Bs1 = smem + 8192;

    const int tid = threadIdx.x;
    const int wave = tid >> 6, lane = tid & 63;
    const int quad = lane >> 4, l16 = lane & 15;
    const int m0 = blockIdx.x * 64, n0 = blockIdx.y * 128;
    const int wm = (wave >> 1) * 32, wn = (wave & 1) * 64;

    f32x4 acc[2][4];
#pragma unroll
    for (int i = 0; i < 2; ++i)
#pragma unroll
        for (int j = 0; j < 4; ++j) acc[i][j] = (f32x4){0.f, 0.f, 0.f, 0.f};

    const int lrow = lane >> 2, lcol = (lane & 3) * 8;

    for (int k0 = 0; k0 < 1024; k0 += 64) {
        {
            const unsigned short* ab = A + (size_t)(m0 + wave * 16 + lrow) * 1024 + k0 + lcol;
            gl_lds16(ab,      &As0[wave * 512]);
            gl_lds16(ab + 32, &As1[wave * 512]);
        }
#pragma unroll
        for (int i = 0; i < 2; ++i) {
            const int c = wave * 2 + i;
            const unsigned short* bb = Bt + (size_t)(n0 + c * 16 + lrow) * 1024 + k0 + lcol;
            gl_lds16(bb,      &Bs0[c * 512]);
            gl_lds16(bb + 32, &Bs1[c * 512]);
        }
        __syncthreads();
        {
            bf16x8 af[2], bfr[4];
#pragma unroll
            for (int mt = 0; mt < 2; ++mt)
                af[mt] = *(const bf16x8*)&As0[(wm + mt * 16 + l16) * 32 + quad * 8];
#pragma unroll
            for (int nt = 0; nt < 4; ++nt)
                bfr[nt] = *(const bf16x8*)&Bs0[(wn + nt * 16 + l16) * 32 + quad * 8];
#pragma unroll
            for (int mt = 0; mt < 2; ++mt)
#pragma unroll
                for (int nt = 0; nt < 4; ++nt)
                    acc[mt][nt] = MFMA16(af[mt], bfr[nt], acc[mt][nt]);
        }
        {
            bf16x8 af[2], bfr[4];
#pragma unroll
            for (int mt = 0; mt < 2; ++mt)
                af[mt] = *(const bf16x8*)&As1[(wm + mt * 16 + l16) * 32 + quad * 8];
#pragma unroll
            for (int nt = 0; nt < 4; ++nt)
                bfr[nt] = *(const bf16x8*)&Bs1[(wn + nt * 16 + l16) * 32 + quad * 8];
#pragma unroll
            for (int mt = 0; mt < 2; ++mt)
#pragma unroll
                for (int nt = 0; nt < 4; ++nt)
                    acc[mt][nt] = MFMA16(af[mt], bfr[nt], acc[mt][nt]);
        }
        __syncthreads();
    }

    unsigned short* tbw = smem + wave * 1152;
    const int region = blockIdx.y >> 3;
    const int h = ((blockIdx.y & 7) << 1) + (wave & 1);

    if (region < 2) {
        const float* wgt = region ? kw : qw;
        unsigned short* dst = region ? Kb : Qb;
        const float post = region ? 1.f : 0.17312340490667046f;
        float w[4];
#pragma unroll
        for (int nt = 0; nt < 4; ++nt) w[nt] = wgt[nt * 16 + l16] * post;
#pragma unroll
        for (int mt = 0; mt < 2; ++mt) {
#pragma unroll
            for (int r = 0; r < 4; ++r) {
                const int row = m0 + wm + mt * 16 + quad * 4 + r;
                float ss = 0.f;
#pragma unroll
                for (int nt = 0; nt < 4; ++nt)
                    ss += acc[mt][nt][r] * acc[mt][nt][r];
                ss += __shfl_xor(ss, 1); ss += __shfl_xor(ss, 2);
                ss += __shfl_xor(ss, 4); ss += __shfl_xor(ss, 8);
                const float rn = rsqrtf(ss * (1.f / 64.f) + 1e-6f);
                float val[4];
#pragma unroll
                for (int nt = 0; nt < 4; ++nt)
                    val[nt] = acc[mt][nt][r] * rn * w[nt];
#pragma unroll
                for (int nt = 0; nt < 2; ++nt) {
                    const float prt = __shfl_xor(val[nt], 1);
                    const int p = nt * 8 + (l16 >> 1);
                    const float c = cosb[row * 16 + p];
                    const float s = sinb[row * 16 + p];
                    val[nt] = (l16 & 1) ? (prt * s + val[nt] * c)
                                        : (val[nt] * c - prt * s);
                }
#pragma unroll
                for (int nt = 0; nt < 4; ++nt)
                    tbw[(quad * 4 + r) * TBS + nt * 16 + l16] = f2bf(val[nt]);
            }
            const int t = lane >> 2, dcol = (lane & 3) * 16;
            u16x8 v0 = *(const u16x8*)&tbw[t * TBS + dcol];
            u16x8 v1 = *(const u16x8*)&tbw[t * TBS + dcol + 8];
            const size_t ob = ((size_t)h * 4096 + (m0 + wm + mt * 16 + t)) * 64 + dcol;
            *(u16x8*)&dst[ob] = v0;
            *(u16x8*)&dst[ob + 8] = v1;
        }
    } else {
#pragma unroll
        for (int mt = 0; mt < 2; ++mt) {
#pragma unroll
            for (int nt = 0; nt < 4; ++nt)
#pragma unroll
                for (int r = 0; r < 4; ++r)
                    tbw[(nt * 16 + l16) * 16 + quad * 4 + r] =
                        f2bf(acc[mt][nt][r] * 0.5f);
            u16x8 v0 = *(const u16x8*)&tbw[lane * 16];
            u16x8 v1 = *(const u16x8*)&tbw[lane * 16 + 8];
            const size_t vo = ((size_t)h * 64 + lane) * 4096 + m0 + wm + mt * 16;
            *(u16x8*)&Vt[vo] = v0;
            *(u16x8*)&Vt[vo + 8] = v1;
        }
    }
}

// ---------------- K2: sliding-window flash attention (R8-exact) ----------
// 4 waves/block, 64 queries/block, 64-key tiles, K AND V staged in LDS
// (single-buffer). XCD swizzle: bid&7 = head-pair. LPT: t descending.
#define PSTR 72  // P row stride (>=64 required; 144 B, 16B-aligned)

template <int MODE>
__device__ __forceinline__ void attn_step(
    int s0, int tq, int wave, int quad, int l16, int krow, int kcol,
    const unsigned short* __restrict__ Kh, const unsigned short* __restrict__ Vh,
    unsigned short* Ks0, unsigned short* Ks1,
    unsigned short* Vs0, unsigned short* Vs1, unsigned short* Pw,
    const bf16x8 qf0, const bf16x8 qf1, f32x4 (&o)[4], float& lsum)
{
    __syncthreads();  // all waves done reading previous K/V tiles
    const unsigned short* kb = Kh + (size_t)(s0 + krow) * 64 + kcol;
    const unsigned short* vb = Vh + (size_t)krow * 4096 + s0 + kcol;
    gl_lds16(kb,      &Ks0[wave * 512]);
    gl_lds16(kb + 32, &Ks1[wave * 512]);
    gl_lds16(vb,      &Vs0[wave * 512]);
    gl_lds16(vb + 32, &Vs1[wave * 512]);
    __syncthreads();  // staging complete

#pragma unroll
    for (int i = 0; i < 4; ++i) {
        // Z_i = K_i * Q^T: A-frag = K rows (contiguous d); C: row=key col=query
        const bf16x8 kf0 = *(const bf16x8*)&Ks0[(i * 16 + l16) * 32 + quad * 8];
        const bf16x8 kf1 = *(const bf16x8*)&Ks1[(i * 16 + l16) * 32 + quad * 8];
        f32x4 z = (f32x4){0.f, 0.f, 0.f, 0.f};
        z = MFMA16(kf0, qf0, z);
        z = MFMA16(kf1, qf1, z);
        float p[4];
#pragma unroll
        for (int r = 0; r < 4; ++r) {
            float e = fexp2(z[r]);   // scale pre-folded into Q
            if (MODE == 1) {
                const int s = s0 + i * 16 + quad * 4 + r;
                e = ((tq - s) < 1024) ? e : 0.f;
            }
            if (MODE == 2) {
                const int s = s0 + i * 16 + quad * 4 + r;
                e = (s <= tq) ? e : 0.f;
            }
            p[r] = e;
            lsum += e;
        }
        uint2 pk;
        pk.x = pk2bf(p[0], p[1]);
        pk.y = pk2bf(p[2], p[3]);
        *(uint2*)&Pw[l16 * PSTR + i * 16 + quad * 4] = pk;
    }
    // P read (A-operand) — wave-private, lgkmcnt ordering suffices
    const bf16x8 pf0 = *(const bf16x8*)&Pw[l16 * PSTR + quad * 8];
    const bf16x8 pf1 = *(const bf16x8*)&Pw[l16 * PSTR + 32 + quad * 8];
#pragma unroll
    for (int dt = 0; dt < 4; ++dt) {
        const bf16x8 vf0 = *(const bf16x8*)&Vs0[(dt * 16 + l16) * 32 + quad * 8];
        const bf16x8 vf1 = *(const bf16x8*)&Vs1[(dt * 16 + l16) * 32 + quad * 8];
        o[dt] = MFMA16(pf0, vf0, o[dt]);
        o[dt] = MFMA16(pf1, vf1, o[dt]);
    }
}

__global__ __launch_bounds__(256) void attn_kernel(
    const unsigned short* __restrict__ Qb,  // [H][T][64] (pre-scaled)
    const unsigned short* __restrict__ Kb,  // [H][T][64]
    const unsigned short* __restrict__ Vt,  // [H][64][T] (pre-scaled by 0.5)
    unsigned short* __restrict__ att)       // [T][1024]
{
    __shared__ unsigned short Ks0[64 * 32];
    __shared__ unsigned short Ks1[64 * 32];
    __shared__ unsigned short Vs0[64 * 32];
    __shared__ unsigned short Vs1[64 * 32];
    __shared__ unsigned short P[4][16 * PSTR];

    // swizzle: h-pair = bid&7 (XCD locality); t descending (LPT balance)
    const int bid = blockIdx.x;
    const int h = ((bid & 7) << 1) | ((bid >> 3) & 1);
    const int t0 = (63 - (bid >> 4)) * 64;

    const int tid = threadIdx.x;
    const int wave = tid >> 6, lane = tid & 63;
    const int quad = lane >> 4, l16 = lane & 15;
    const int qt0 = t0 + wave * 16;
    const int tq = qt0 + l16;        // this lane's query (S^T col)
    const int krow = tid >> 2, kcol = (tid & 3) * 8;

    const unsigned short* Qh = Qb + (size_t)h * 4096 * 64;
    const unsigned short* Kh = Kb + (size_t)h * 4096 * 64;
    const unsigned short* Vh = Vt + (size_t)h * 64 * 4096;

    const bf16x8 qf0 = *(const bf16x8*)&Qh[(qt0 + l16) * 64 + quad * 8];
    const bf16x8 qf1 = *(const bf16x8*)&Qh[(qt0 + l16) * 64 + 32 + quad * 8];

    f32x4 o[4];
#pragma unroll
    for (int dt = 0; dt < 4; ++dt) o[dt] = (f32x4){0.f, 0.f, 0.f, 0.f};
    float lsum = 0.f;
    unsigned short* Pw = P[wave];

    int s0 = (t0 >= 1024) ? (t0 - 1024) : 0;
    if (t0 >= 1024) {  // first tile: window mask
        attn_step<1>(s0, tq, wave, quad, l16, krow, kcol, Kh, Vh,
                     Ks0, Ks1, Vs0, Vs1, Pw, qf0, qf1, o, lsum);
        s0 += 64;
    }
    for (; s0 < t0; s0 += 64)  // interior: no masks
        attn_step<0>(s0, tq, wave, quad, l16, krow, kcol, Kh, Vh,
                     Ks0, Ks1, Vs0, Vs1, Pw, qf0, qf1, o, lsum);
    attn_step<2>(t0, tq, wave, quad, l16, krow, kcol, Kh, Vh,
                 Ks0, Ks1, Vs0, Vs1, Pw, qf0, qf1, o, lsum);

    lsum += __shfl_xor(lsum, 16);
    lsum += __shfl_xor(lsum, 32);
    float lr[4];
#pragma unroll
    for (int r = 0; r < 4; ++r) lr[r] = 1.f / __shfl(lsum, quad * 4 + r);
#pragma unroll
    for (int dt = 0; dt < 4; ++dt)
#pragma unroll
        for (int r = 0; r < 4; ++r)
            att[(size_t)(qt0 + quad * 4 + r) * 1024 + h * 64 + dt * 16 + l16] =
                f2bf(o[dt][r] * lr[r]);
}

// ---------------- K3: output GEMM (BM=64, BN=64, BK=64, prefetch-dbuf) ----
// THIS ROUND: 1024 blocks = 4/CU, 16 waves/CU (was 512 = 2/CU supply-starved).
// XCD-chunked remap: XCD j owns wg [j*128, j*128+128) = 8 m-rows x 16 n-cols
// -> per-XCD L2 working set = A-panel 1MB + full B 2MB = 3MB < 4MB L2.
__global__ __launch_bounds__(256) void gemm_out(
    const unsigned short* __restrict__ A,    // attb [4096][1024]
    const unsigned short* __restrict__ Bt,   // wob  [1024][1024]
    float* __restrict__ C)                   // [4096][1024]
{
    __shared__ unsigned short As0[2][2048], As1[2][2048];
    __shared__ unsigned short Bs0[2][2048], Bs1[2][2048];
    const int tid = threadIdx.x;
    const int wave = tid >> 6, lane = tid & 63;
    const int quad = lane >> 4, l16 = lane & 15;
    // bijective XCD remap (nwg=1024, nwg%8==0)
    const int wg = (blockIdx.x & 7) * 128 + (blockIdx.x >> 3);
    const int m0 = (wg >> 4) * 64, n0 = (wg & 15) * 64;
    const int wm = (wave >> 1) * 32, wn = (wave & 1) * 32;
    const int row = wave * 16 + (lane >> 2), col = (lane & 3) * 8;

    f32x4 acc[2][2];
#pragma unroll
    for (int i = 0; i < 2; ++i)
#pragma unroll
        for (int j = 0; j < 2; ++j) acc[i][j] = (f32x4){0.f, 0.f, 0.f, 0.f};

    auto stage = [&](int buf, int k0) {
        const unsigned short* ab = A + (size_t)(m0 + row) * 1024 + k0 + col;
        gl_lds16(ab,      &As0[buf][wave * 512]);
        gl_lds16(ab + 32, &As1[buf][wave * 512]);
        const unsigned short* bb = Bt + (size_t)(n0 + row) * 1024 + k0 + col;
        gl_lds16(bb,      &Bs0[buf][wave * 512]);
        gl_lds16(bb + 32, &Bs1[buf][wave * 512]);
    };

    stage(0, 0);
    __syncthreads();
    int buf = 0;
    for (int k0 = 0; k0 < 1024; k0 += 64) {
        if (k0 + 64 < 1024) stage(buf ^ 1, k0 + 64);  // prefetch before compute
        {
            bf16x8 af[2], bfr[2];
#pragma unroll
            for (int mt = 0; mt < 2; ++mt)
                af[mt] = *(const bf16x8*)&As0[buf][(wm + mt * 16 + l16) * 32 + quad * 8];
#pragma unroll
            for (int nt = 0; nt < 2; ++nt)
                bfr[nt] = *(const bf16x8*)&Bs0[buf][(wn + nt * 16 + l16) * 32 + quad * 8];
#pragma unroll
            for (int mt = 0; mt < 2; ++mt)
#pragma unroll
                for (int nt = 0; nt < 2; ++nt)
                    acc[mt][nt] = MFMA16(af[mt], bfr[nt], acc[mt][nt]);
        }
        {
            bf16x8 af[2], bfr[2];
#pragma unroll
            for (int mt = 0; mt < 2; ++mt)
                af[mt] = *(const bf16x8*)&As1[buf][(wm + mt * 16 + l16) * 32 + quad * 8];
#pragma unroll
            for (int nt = 0; nt < 2; ++nt)
                bfr[nt] = *(const bf16x8*)&Bs1[buf][(wn + nt * 16 + l16) * 32 + quad * 8];
#pragma unroll
            for (int mt = 0; mt < 2; ++mt)
#pragma unroll
                for (int nt = 0; nt < 2; ++nt)
                    acc[mt][nt] = MFMA16(af[mt], bfr[nt], acc[mt][nt]);
        }
        __syncthreads();  // publishes prefetched tiles; protects buf reuse
        buf ^= 1;
    }
#pragma unroll
    for (int mt = 0; mt < 2; ++mt)
#pragma unroll
        for (int nt = 0; nt < 2; ++nt)
#pragma unroll
            for (int r = 0; r < 4; ++r) {
                const int row2 = m0 + wm + mt * 16 + quad * 4 + r;
                const int col2 = n0 + wn + nt * 16 + l16;
                C[(size_t)row2 * 1024 + col2] = acc[mt][nt][r];
            }
}

// ---------------- launcher ----------------
extern "C" void kernel_launch(void* const* d_in, const int* in_sizes, int n_in,
                              void* d_out, int out_size, void* d_ws, size_t ws_size,
                              hipStream_t stream) {
    const float* x    = (const float*)d_in[0];
    const float* wqkv = (const float*)d_in[3];
    const float* wo   = (const float*)d_in[4];
    const float* qw   = (const float*)d_in[5];
    const float* kw   = (const float*)d_in[6];
    const float* cosb = (const float*)d_in[7];
    const float* sinb = (const float*)d_in[8];

    char* ws = (char*)d_ws;
    // ws (MiB): xb 0-8 | wqkvb 8-14 | wob 14-16 | Qb 16-24 | Kb 24-32
    //           Vt 32-40 | attb 40-48
    if (ws_size < (size_t)48 * 1024 * 1024) return;
    unsigned short* xb    = (unsigned short*)(ws + ((size_t)0 << 20));
    unsigned short* wqkvb = (unsigned short*)(ws + ((size_t)8 << 20));
    unsigned short* wob   = (unsigned short*)(ws + ((size_t)14 << 20));
    unsigned short* Qb    = (unsigned short*)(ws + ((size_t)16 << 20));
    unsigned short* Kb    = (unsigned short*)(ws + ((size_t)24 << 20));
    unsigned short* Vt    = (unsigned short*)(ws + ((size_t)32 << 20));
    unsigned short* attb  = (unsigned short*)(ws + ((size_t)40 << 20));

    // K0: fused converts (one launch)
    cvt3_kernel<<<8192, 256, 0, stream>>>(x, wqkv, wo, xb, wqkvb, wob);

    // K1: qkv GEMM + fused rmsnorm/rope/pack epilogue (64x128x64 tiles, 6/CU)
    gemm_qkv<<<dim3(64, 24), 256, 0, stream>>>(xb, wqkvb, cosb, sinb, qw, kw,
                                               Qb, Kb, Vt);

    // K2: sliding-window attention (R8-exact staged K+V; XCD+LPT swizzle)
    attn_kernel<<<1024, 256, 0, stream>>>(Qb, Kb, Vt, attb);

    // K3: y = att @ w_o^T  (M=4096, N=1024, K=1024), fp32 out, 64x64 tiles,
    //     1024 blocks (4/CU), XCD-chunked, prefetch-dbuf
    gemm_out<<<1024, 256, 0, stream>>>(attb, wob, (float*)d_out);
}

// Round 2
// 179.550 us; speedup vs baseline: 1.0403x; 1.0403x over previous
//
#include <hip/hip_runtime.h>

// Problem constants (hardcoded from reference):
//   T=4096, D_MODEL=1024, N_HEADS=16, HEAD_DIM=64, ROT=32, PAIR=16,
//   EPS=1e-6, SCALE=0.12, WINDOW=1024. tokens/pos/block_size unused.
//
// Attention numerics: rmsnorm => ||q||=||k||=8, so |q.k|*SCALE <= 7.68 ->
// exp bounded [4.6e-4, 2164]: softmax max-subtraction unnecessary.
// SCALE*log2(e) pre-folded into Q at the gemm_qkv epilogue: p = exp2(z).
//
// R2 changes (theory: attn is latency+bank-conflict bound; 5.36M conflicts,
// 1.7k cy/step vs ~500 cy compute):
//  - ALL LDS tiles ([rows][32-short], 64B row stride) had a 4-way read
//    conflict: chunk c of row r now stored at c^((r>>1)&3). Staged via
//    pre-swizzled GLOBAL source (gl_lds dest stays linear), read with the
//    same XOR -> conflict-free (verified per-8-lane-group bank mapping).
//    Applied to attn K/V, gemm_qkv A/B, gemm_out A/B.
//  - attn: K/V double-buffered; prefetch issued BEFORE compute, ONE barrier
//    per step (gemm_out-style). LDS 25.6->42KB (3 blocks/CU) but removes the
//    per-step full vmcnt(0) latency exposure.
//  - gemm_out: reverted to session-measured-best 64x128 512-block dbuf.

typedef __bf16 bf16x8 __attribute__((ext_vector_type(8)));
typedef __bf16 bf16x2 __attribute__((ext_vector_type(2)));
typedef float f32x4 __attribute__((ext_vector_type(4)));
typedef unsigned short u16x8 __attribute__((ext_vector_type(8)));
typedef unsigned short u16x4 __attribute__((ext_vector_type(4)));

#define MFMA16(a, b, c) __builtin_amdgcn_mfma_f32_16x16x32_bf16((a), (b), (c), 0, 0, 0)

__device__ __forceinline__ unsigned short f2bf(float f) {
    unsigned int u = __float_as_uint(f);
    u += 0x7fffu + ((u >> 16) & 1u);   // round-to-nearest-even
    return (unsigned short)(u >> 16);
}
__device__ __forceinline__ float bf2f(unsigned short h) {
    return __uint_as_float(((unsigned int)h) << 16);
}
__device__ __forceinline__ unsigned int pk2bf(float a, float b) {
#if __has_builtin(__builtin_amdgcn_cvt_pk_bf16_f32)
    bf16x2 v = __builtin_amdgcn_cvt_pk_bf16_f32(a, b);
    return __builtin_bit_cast(unsigned int, v);
#else
    return (unsigned int)f2bf(a) | ((unsigned int)f2bf(b) << 16);
#endif
}
__device__ __forceinline__ float fexp2(float x) {
#if __has_builtin(__builtin_amdgcn_exp2f)
    return __builtin_amdgcn_exp2f(x);   // raw v_exp_f32; args bounded +-1.33
#else
    return exp2f(x);
#endif
}

// async global->LDS, 16B per lane; LDS dest = wave-uniform base + lane*16
__device__ __forceinline__ void gl_lds16(const void* g, void* l) {
    typedef __attribute__((address_space(1))) unsigned int GU;
    typedef __attribute__((address_space(3))) unsigned int LU;
    __builtin_amdgcn_global_load_lds((GU*)(unsigned long long)g,
                                     (LU*)(unsigned int)(unsigned long long)l,
                                     16, 0, 0);
}

// ---------------- K0: fused fp32 -> bf16 convert (x, w_qkv, w_o) ----------
__global__ void cvt3_kernel(const float* __restrict__ x,
                            const float* __restrict__ wqkv,
                            const float* __restrict__ wo,
                            unsigned short* __restrict__ xb,
                            unsigned short* __restrict__ wqkvb,
                            unsigned short* __restrict__ wob) {
    int i = blockIdx.x * 256 + threadIdx.x;
    const float* src;
    unsigned short* dst;
    int off;
    if (i < 1048576) { src = x; dst = xb; off = i; }
    else if (i < 1835008) { src = wqkv; dst = wqkvb; off = i - 1048576; }
    else { src = wo; dst = wob; off = i - 1835008; }
    float4 f = ((const float4*)src)[off];
    u16x4 o;
    o[0] = f2bf(f.x); o[1] = f2bf(f.y); o[2] = f2bf(f.z); o[3] = f2bf(f.w);
    ((u16x4*)dst)[off] = o;
}

// ---------------- K1: qkv GEMM + fused rmsnorm/rope/pack epilogue ----------
// (R9 config: 64x128xBK64 single-buffer, 6/CU, aliased epilogue LDS)
// + R2: XOR bank-swizzle on A/B tiles (staging source + fragment reads).
#define TBS 72
__global__ __launch_bounds__(256, 6) void gemm_qkv(
    const unsigned short* __restrict__ A,    // xb [4096][1024]
    const unsigned short* __restrict__ Bt,   // wqkvb [3072][1024]
    const float* __restrict__ cosb, const float* __restrict__ sinb,  // [T][16]
    const float* __restrict__ qw, const float* __restrict__ kw,      // [64]
    unsigned short* __restrict__ Qb,  // [H][T][64] (pre-scaled)
    unsigned short* __restrict__ Kb,  // [H][T][64]
    unsigned short* __restrict__ Vt)  // [H][64][T] (pre-scaled by 0.5)
{
    __shared__ unsigned short smem[12288];  // 24 KB
    unsigned short* As0 = smem;
    unsigned short* As1 = smem + 2048;
    unsigned short* Bs0 = smem + 4096;
    unsigned short* Bs1 = smem + 8192;

    const int tid = threadIdx.x;
    const int wave = tid >> 6, lane = tid & 63;
    const int quad = lane >> 4, l16 = lane & 15;
    const int m0 = blockIdx.x * 64, n0 = blockIdx.y * 128;
    const int wm = (wave >> 1) * 32, wn = (wave & 1) * 64;

    f32x4 acc[2][4];
#pragma unroll
    for (int i = 0; i < 2; ++i)
#pragma unroll
        for (int j = 0; j < 4; ++j) acc[i][j] = (f32x4){0.f, 0.f, 0.f, 0.f};

    const int lrow = lane >> 2;
    const int lcol = ((lane & 3) ^ ((lane >> 3) & 3)) * 8;   // swizzled src chunk
    const int csw  = (quad ^ ((l16 >> 1) & 3)) * 8;          // swizzled read chunk

    for (int k0 = 0; k0 < 1024; k0 += 64) {
        {
            const unsigned short* ab = A + (size_t)(m0 + wave * 16 + lrow) * 1024 + k0 + lcol;
            gl_lds16(ab,      &As0[wave * 512]);
            gl_lds16(ab + 32, &As1[wave * 512]);
        }
#pragma unroll
        for (int i = 0; i < 2; ++i) {
            const int c = wave * 2 + i;
            const unsigned short* bb = Bt + (size_t)(n0 + c * 16 + lrow) * 1024 + k0 + lcol;
            gl_lds16(bb,      &Bs0[c * 512]);
            gl_lds16(bb + 32, &Bs1[c * 512]);
        }
        __syncthreads();
        {
            bf16x8 af[2], bfr[4];
#pragma unroll
            for (int mt = 0; mt < 2; ++mt)
                af[mt] = *(const bf16x8*)&As0[(wm + mt * 16 + l16) * 32 + csw];
#pragma unroll
            for (int nt = 0; nt < 4; ++nt)
                bfr[nt] = *(const bf16x8*)&Bs0[(wn + nt * 16 + l16) * 32 + csw];
#pragma unroll
            for (int mt = 0; mt < 2; ++mt)
#pragma unroll
                for (int nt = 0; nt < 4; ++nt)
                    acc[mt][nt] = MFMA16(af[mt], bfr[nt], acc[mt][nt]);
        }
        {
            bf16x8 af[2], bfr[4];
#pragma unroll
            for (int mt = 0; mt < 2; ++mt)
                af[mt] = *(const bf16x8*)&As1[(wm + mt * 16 + l16) * 32 + csw];
#pragma unroll
            for (int nt = 0; nt < 4; ++nt)
                bfr[nt] = *(const bf16x8*)&Bs1[(wn + nt * 16 + l16) * 32 + csw];
#pragma unroll
            for (int mt = 0; mt < 2; ++mt)
#pragma unroll
                for (int nt = 0; nt < 4; ++nt)
                    acc[mt][nt] = MFMA16(af[mt], bfr[nt], acc[mt][nt]);
        }
        __syncthreads();
    }

    unsigned short* tbw = smem + wave * 1152;
    const int region = blockIdx.y >> 3;
    const int h = ((blockIdx.y & 7) << 1) + (wave & 1);

    if (region < 2) {
        const float* wgt = region ? kw : qw;
        unsigned short* dst = region ? Kb : Qb;
        const float post = region ? 1.f : 0.17312340490667046f;
        float w[4];
#pragma unroll
        for (int nt = 0; nt < 4; ++nt) w[nt] = wgt[nt * 16 + l16] * post;
#pragma unroll
        for (int mt = 0; mt < 2; ++mt) {
#pragma unroll
            for (int r = 0; r < 4; ++r) {
                const int row = m0 + wm + mt * 16 + quad * 4 + r;
                float ss = 0.f;
#pragma unroll
                for (int nt = 0; nt < 4; ++nt)
                    ss += acc[mt][nt][r] * acc[mt][nt][r];
                ss += __shfl_xor(ss, 1); ss += __shfl_xor(ss, 2);
                ss += __shfl_xor(ss, 4); ss += __shfl_xor(ss, 8);
                const float rn = rsqrtf(ss * (1.f / 64.f) + 1e-6f);
                float val[4];
#pragma unroll
                for (int nt = 0; nt < 4; ++nt)
                    val[nt] = acc[mt][nt][r] * rn * w[nt];
#pragma unroll
                for (int nt = 0; nt < 2; ++nt) {
                    const float prt = __shfl_xor(val[nt], 1);
                    const int p = nt * 8 + (l16 >> 1);
                    const float c = cosb[row * 16 + p];
                    const float s = sinb[row * 16 + p];
                    val[nt] = (l16 & 1) ? (prt * s + val[nt] * c)
                                        : (val[nt] * c - prt * s);
                }
#pragma unroll
                for (int nt = 0; nt < 4; ++nt)
                    tbw[(quad * 4 + r) * TBS + nt * 16 + l16] = f2bf(val[nt]);
            }
            const int t = lane >> 2, dcol = (lane & 3) * 16;
            u16x8 v0 = *(const u16x8*)&tbw[t * TBS + dcol];
            u16x8 v1 = *(const u16x8*)&tbw[t * TBS + dcol + 8];
            const size_t ob = ((size_t)h * 4096 + (m0 + wm + mt * 16 + t)) * 64 + dcol;
            *(u16x8*)&dst[ob] = v0;
            *(u16x8*)&dst[ob + 8] = v1;
        }
    } else {
#pragma unroll
        for (int mt = 0; mt < 2; ++mt) {
#pragma unroll
            for (int nt = 0; nt < 4; ++nt)
#pragma unroll
                for (int r = 0; r < 4; ++r)
                    tbw[(nt * 16 + l16) * 16 + quad * 4 + r] =
                        f2bf(acc[mt][nt][r] * 0.5f);
            u16x8 v0 = *(const u16x8*)&tbw[lane * 16];
            u16x8 v1 = *(const u16x8*)&tbw[lane * 16 + 8];
            const size_t vo = ((size_t)h * 64 + lane) * 4096 + m0 + wm + mt * 16;
            *(u16x8*)&Vt[vo] = v0;
            *(u16x8*)&Vt[vo + 8] = v1;
        }
    }
}

// ---------------- K2: sliding-window flash attention ----------------------
// R2: K/V double-buffered, prefetch-before-compute, ONE barrier per step;
// XOR bank-swizzle on K/V tiles. 4 waves/block, 64 queries, 64-key tiles.
// LDS = 32KB K/V dbuf + 9KB P = 41KB -> 3 blocks/CU.
#define PSTR 72  // P row stride (>=64 required; 144 B, 16B-aligned)

template <int MODE>
__device__ __forceinline__ void attn_compute(
    int s0, int tq, int quad, int l16, int csw,
    const unsigned short* Ks0, const unsigned short* Ks1,
    const unsigned short* Vs0, const unsigned short* Vs1,
    unsigned short* Pw, const bf16x8 qf0, const bf16x8 qf1,
    f32x4 (&o)[4], float& lsum)
{
#pragma unroll
    for (int i = 0; i < 4; ++i) {
        // Z_i = K_i * Q^T: A-frag = K rows (contiguous d); C: row=key col=query
        const bf16x8 kf0 = *(const bf16x8*)&Ks0[(i * 16 + l16) * 32 + csw];
        const bf16x8 kf1 = *(const bf16x8*)&Ks1[(i * 16 + l16) * 32 + csw];
        f32x4 z = (f32x4){0.f, 0.f, 0.f, 0.f};
        z = MFMA16(kf0, qf0, z);
        z = MFMA16(kf1, qf1, z);
        float p[4];
#pragma unroll
        for (int r = 0; r < 4; ++r) {
            float e = fexp2(z[r]);   // scale pre-folded into Q
            if (MODE == 1) {
                const int s = s0 + i * 16 + quad * 4 + r;
                e = ((tq - s) < 1024) ? e : 0.f;
            }
            if (MODE == 2) {
                const int s = s0 + i * 16 + quad * 4 + r;
                e = (s <= tq) ? e : 0.f;
            }
            p[r] = e;
            lsum += e;
        }
        uint2 pk;
        pk.x = pk2bf(p[0], p[1]);
        pk.y = pk2bf(p[2], p[3]);
        *(uint2*)&Pw[l16 * PSTR + i * 16 + quad * 4] = pk;
    }
    // P read (A-operand) — wave-private, lgkmcnt ordering suffices
    const bf16x8 pf0 = *(const bf16x8*)&Pw[l16 * PSTR + quad * 8];
    const bf16x8 pf1 = *(const bf16x8*)&Pw[l16 * PSTR + 32 + quad * 8];
#pragma unroll
    for (int dt = 0; dt < 4; ++dt) {
        const bf16x8 vf0 = *(const bf16x8*)&Vs0[(dt * 16 + l16) * 32 + csw];
        const bf16x8 vf1 = *(const bf16x8*)&Vs1[(dt * 16 + l16) * 32 + csw];
        o[dt] = MFMA16(pf0, vf0, o[dt]);
        o[dt] = MFMA16(pf1, vf1, o[dt]);
    }
}

__global__ __launch_bounds__(256) void attn_kernel(
    const unsigned short* __restrict__ Qb,  // [H][T][64] (pre-scaled)
    const unsigned short* __restrict__ Kb,  // [H][T][64]
    const unsigned short* __restrict__ Vt,  // [H][64][T] (pre-scaled by 0.5)
    unsigned short* __restrict__ att)       // [T][1024]
{
    __shared__ unsigned short Ks0[2][2048], Ks1[2][2048];
    __shared__ unsigned short Vs0[2][2048], Vs1[2][2048];
    __shared__ unsigned short P[4][16 * PSTR];

    // swizzle: h-pair = bid&7 (XCD locality); t descending (LPT balance)
    const int bid = blockIdx.x;
    const int h = ((bid & 7) << 1) | ((bid >> 3) & 1);
    const int t0 = (63 - (bid >> 4)) * 64;

    const int tid = threadIdx.x;
    const int wave = tid >> 6, lane = tid & 63;
    const int quad = lane >> 4, l16 = lane & 15;
    const int qt0 = t0 + wave * 16;
    const int tq = qt0 + l16;        // this lane's query (S^T col)
    const int krow = tid >> 2;
    const int kcol = ((tid & 3) ^ ((tid >> 3) & 3)) * 8;   // swizzled src chunk
    const int csw  = (quad ^ ((l16 >> 1) & 3)) * 8;        // swizzled read chunk

    const unsigned short* Qh = Qb + (size_t)h * 4096 * 64;
    const unsigned short* Kh = Kb + (size_t)h * 4096 * 64;
    const unsigned short* Vh = Vt + (size_t)h * 64 * 4096;

    const bf16x8 qf0 = *(const bf16x8*)&Qh[(qt0 + l16) * 64 + quad * 8];
    const bf16x8 qf1 = *(const bf16x8*)&Qh[(qt0 + l16) * 64 + 32 + quad * 8];

    f32x4 o[4];
#pragma unroll
    for (int dt = 0; dt < 4; ++dt) o[dt] = (f32x4){0.f, 0.f, 0.f, 0.f};
    float lsum = 0.f;
    unsigned short* Pw = P[wave];

    auto stage = [&](int b, int s0) {
        const unsigned short* kb = Kh + (size_t)(s0 + krow) * 64 + kcol;
        const unsigned short* vb = Vh + (size_t)krow * 4096 + s0 + kcol;
        gl_lds16(kb,      &Ks0[b][wave * 512]);
        gl_lds16(kb + 32, &Ks1[b][wave * 512]);
        gl_lds16(vb,      &Vs0[b][wave * 512]);
        gl_lds16(vb + 32, &Vs1[b][wave * 512]);
    };

    int s0 = (t0 >= 1024) ? (t0 - 1024) : 0;
    stage(0, s0);
    __syncthreads();               // compiler drains vmcnt(0) here
    int buf = 0;

    if (t0 >= 1024) {  // first tile: window mask (always has a next tile)
        stage(1, s0 + 64);
        attn_compute<1>(s0, tq, quad, l16, csw, Ks0[0], Ks1[0], Vs0[0], Vs1[0],
                        Pw, qf0, qf1, o, lsum);
        __syncthreads();           // prefetch landed + all waves done reading
        buf = 1; s0 += 64;
    }
    for (; s0 < t0; s0 += 64) {    // interior: no masks; next tile always exists
        stage(buf ^ 1, s0 + 64);
        attn_compute<0>(s0, tq, quad, l16, csw, Ks0[buf], Ks1[buf], Vs0[buf],
                        Vs1[buf], Pw, qf0, qf1, o, lsum);
        __syncthreads();
        buf ^= 1;
    }
    // final (diagonal) tile: staged by the last loop iteration (or prologue)
    attn_compute<2>(t0, tq, quad, l16, csw, Ks0[buf], Ks1[buf], Vs0[buf],
                    Vs1[buf], Pw, qf0, qf1, o, lsum);

    lsum += __shfl_xor(lsum, 16);
    lsum += __shfl_xor(lsum, 32);
    float lr[4];
#pragma unroll
    for (int r = 0; r < 4; ++r) lr[r] = 1.f / __shfl(lsum, quad * 4 + r);
#pragma unroll
    for (int dt = 0; dt < 4; ++dt)
#pragma unroll
        for (int r = 0; r < 4; ++r)
            att[(size_t)(qt0 + quad * 4 + r) * 1024 + h * 64 + dt * 16 + l16] =
                f2bf(o[dt][r] * lr[r]);
}

// ---------------- K3: output GEMM (BM=64, BN=128, BK=64, prefetch-dbuf) ---
// Session-measured-best config (512 blocks, 2/CU supply-starved regime:
// dbuf is the measured win there). + R2 XOR bank-swizzle.
__global__ __launch_bounds__(256) void gemm_out(
    const unsigned short* __restrict__ A,    // attb [4096][1024]
    const unsigned short* __restrict__ Bt,   // wob  [1024][1024]
    float* __restrict__ C)                   // [4096][1024]
{
    __shared__ unsigned short As0[2][2048], As1[2][2048];
    __shared__ unsigned short Bs0[2][4096], Bs1[2][4096];
    const int tid = threadIdx.x;
    const int wave = tid >> 6, lane = tid & 63;
    const int quad = lane >> 4, l16 = lane & 15;
    const int m0 = blockIdx.x * 64, n0 = blockIdx.y * 128;
    const int wm = (wave >> 1) * 32, wn = (wave & 1) * 64;
    const int lrow = lane >> 2;
    const int lcol = ((lane & 3) ^ ((lane >> 3) & 3)) * 8;   // swizzled src chunk
    const int csw  = (quad ^ ((l16 >> 1) & 3)) * 8;          // swizzled read chunk

    f32x4 acc[2][4];
#pragma unroll
    for (int i = 0; i < 2; ++i)
#pragma unroll
        for (int j = 0; j < 4; ++j) acc[i][j] = (f32x4){0.f, 0.f, 0.f, 0.f};

    auto stage = [&](int buf, int k0) {
        const unsigned short* ab = A + (size_t)(m0 + wave * 16 + lrow) * 1024 + k0 + lcol;
        gl_lds16(ab,      &As0[buf][wave * 512]);
        gl_lds16(ab + 32, &As1[buf][wave * 512]);
#pragma unroll
        for (int i = 0; i < 2; ++i) {
            const int c = wave * 2 + i;
            const unsigned short* bb = Bt + (size_t)(n0 + c * 16 + lrow) * 1024 + k0 + lcol;
            gl_lds16(bb,      &Bs0[buf][c * 512]);
            gl_lds16(bb + 32, &Bs1[buf][c * 512]);
        }
    };

    stage(0, 0);
    __syncthreads();
    int buf = 0;
    for (int k0 = 0; k0 < 1024; k0 += 64) {
        if (k0 + 64 < 1024) stage(buf ^ 1, k0 + 64);  // prefetch before compute
        {
            bf16x8 af[2], bfr[4];
#pragma unroll
            for (int mt = 0; mt < 2; ++mt)
                af[mt] = *(const bf16x8*)&As0[buf][(wm + mt * 16 + l16) * 32 + csw];
#pragma unroll
            for (int nt = 0; nt < 4; ++nt)
                bfr[nt] = *(const bf16x8*)&Bs0[buf][(wn + nt * 16 + l16) * 32 + csw];
#pragma unroll
            for (int mt = 0; mt < 2; ++mt)
#pragma unroll
                for (int nt = 0; nt < 4; ++nt)
                    acc[mt][nt] = MFMA16(af[mt], bfr[nt], acc[mt][nt]);
        }
        {
            bf16x8 af[2], bfr[4];
#pragma unroll
            for (int mt = 0; mt < 2; ++mt)
                af[mt] = *(const bf16x8*)&As1[buf][(wm + mt * 16 + l16) * 32 + csw];
#pragma unroll
            for (int nt = 0; nt < 4; ++nt)
                bfr[nt] = *(const bf16x8*)&Bs1[buf][(wn + nt * 16 + l16) * 32 + csw];
#pragma unroll
            for (int mt = 0; mt < 2; ++mt)
#pragma unroll
                for (int nt = 0; nt < 4; ++nt)
                    acc[mt][nt] = MFMA16(af[mt], bfr[nt], acc[mt][nt]);
        }
        __syncthreads();  // publishes prefetched tiles; protects buf reuse
        buf ^= 1;
    }
#pragma unroll
    for (int mt = 0; mt < 2; ++mt)
#pragma unroll
        for (int nt = 0; nt < 4; ++nt)
#pragma unroll
            for (int r = 0; r < 4; ++r) {
                const int row = m0 + wm + mt * 16 + quad * 4 + r;
                const int col = n0 + wn + nt * 16 + l16;
                C[(size_t)row * 1024 + col] = acc[mt][nt][r];
            }
}

// ---------------- launcher ----------------
extern "C" void kernel_launch(void* const* d_in, const int* in_sizes, int n_in,
                              void* d_out, int out_size, void* d_ws, size_t ws_size,
                              hipStream_t stream) {
    const float* x    = (const float*)d_in[0];
    const float* wqkv = (const float*)d_in[3];
    const float* wo   = (const float*)d_in[4];
    const float* qw   = (const float*)d_in[5];
    const float* kw   = (const float*)d_in[6];
    const float* cosb = (const float*)d_in[7];
    const float* sinb = (const float*)d_in[8];

    char* ws = (char*)d_ws;
    // ws (MiB): xb 0-8 | wqkvb 8-14 | wob 14-16 | Qb 16-24 | Kb 24-32
    //           Vt 32-40 | attb 40-48
    if (ws_size < (size_t)48 * 1024 * 1024) return;
    unsigned short* xb    = (unsigned short*)(ws + ((size_t)0 << 20));
    unsigned short* wqkvb = (unsigned short*)(ws + ((size_t)8 << 20));
    unsigned short* wob   = (unsigned short*)(ws + ((size_t)14 << 20));
    unsigned short* Qb    = (unsigned short*)(ws + ((size_t)16 << 20));
    unsigned short* Kb    = (unsigned short*)(ws + ((size_t)24 << 20));
    unsigned short* Vt    = (unsigned short*)(ws + ((size_t)32 << 20));
    unsigned short* attb  = (unsigned short*)(ws + ((size_t)40 << 20));

    // K0: fused converts (one launch)
    cvt3_kernel<<<8192, 256, 0, stream>>>(x, wqkv, wo, xb, wqkvb, wob);

    // K1: qkv GEMM + fused rmsnorm/rope/pack epilogue (64x128x64 tiles, 6/CU)
    gemm_qkv<<<dim3(64, 24), 256, 0, stream>>>(xb, wqkvb, cosb, sinb, qw, kw,
                                               Qb, Kb, Vt);

    // K2: sliding-window attention (dbuf K/V + swizzle; XCD+LPT swizzle)
    attn_kernel<<<1024, 256, 0, stream>>>(Qb, Kb, Vt, attb);

    // K3: y = att @ w_o^T  (M=4096, N=1024, K=1024), fp32 out, BK64 dbuf
    gemm_out<<<dim3(64, 8), 256, 0, stream>>>(attb, wob, (float*)d_out);
}

// Round 3
// 177.945 us; speedup vs baseline: 1.0496x; 1.0090x over previous
//
#include <hip/hip_runtime.h>

// Problem constants (hardcoded from reference):
//   T=4096, D_MODEL=1024, N_HEADS=16, HEAD_DIM=64, ROT=32, PAIR=16,
//   EPS=1e-6, SCALE=0.12, WINDOW=1024. tokens/pos/block_size unused.
//
// Attention numerics: rmsnorm => ||q||=||k||=8, so |q.k|*SCALE <= 7.68 ->
// exp bounded [4.6e-4, 2164]: softmax max-subtraction unnecessary.
// SCALE*log2(e) pre-folded into Q at the gemm_qkv epilogue: p = exp2(z).
//
// R3 changes:
//  - gemm_qkv: 64x128 -> 128x128 tile (m97 structure): 32 MFMA/wave/K-step,
//    8x gl_lds16/lane, acc[4][4], launch_bounds (256,3) (was (256,6) which
//    capped VGPR at ~85 and forced the small tile). Grid 32x24 = 768 = 3/CU.
//  - attn: 4-wave/64q -> 8-wave/128q blocks: K/V staging amortized 8x (per-
//    query staging halved), 16 waves/CU (was 12), per-wave dead-tile skip,
//    unified unsigned-window mask on boundary tiles only. dbuf + swizzle
//    kept from R2 (measured win).
//  - gemm_out, cvt3: unchanged (R2-measured).

typedef __bf16 bf16x8 __attribute__((ext_vector_type(8)));
typedef __bf16 bf16x2 __attribute__((ext_vector_type(2)));
typedef float f32x4 __attribute__((ext_vector_type(4)));
typedef unsigned short u16x8 __attribute__((ext_vector_type(8)));
typedef unsigned short u16x4 __attribute__((ext_vector_type(4)));

#define MFMA16(a, b, c) __builtin_amdgcn_mfma_f32_16x16x32_bf16((a), (b), (c), 0, 0, 0)

__device__ __forceinline__ unsigned short f2bf(float f) {
    unsigned int u = __float_as_uint(f);
    u += 0x7fffu + ((u >> 16) & 1u);   // round-to-nearest-even
    return (unsigned short)(u >> 16);
}
__device__ __forceinline__ float bf2f(unsigned short h) {
    return __uint_as_float(((unsigned int)h) << 16);
}
__device__ __forceinline__ unsigned int pk2bf(float a, float b) {
#if __has_builtin(__builtin_amdgcn_cvt_pk_bf16_f32)
    bf16x2 v = __builtin_amdgcn_cvt_pk_bf16_f32(a, b);
    return __builtin_bit_cast(unsigned int, v);
#else
    return (unsigned int)f2bf(a) | ((unsigned int)f2bf(b) << 16);
#endif
}
__device__ __forceinline__ float fexp2(float x) {
#if __has_builtin(__builtin_amdgcn_exp2f)
    return __builtin_amdgcn_exp2f(x);   // raw v_exp_f32; args bounded +-1.33
#else
    return exp2f(x);
#endif
}

// async global->LDS, 16B per lane; LDS dest = wave-uniform base + lane*16
__device__ __forceinline__ void gl_lds16(const void* g, void* l) {
    typedef __attribute__((address_space(1))) unsigned int GU;
    typedef __attribute__((address_space(3))) unsigned int LU;
    __builtin_amdgcn_global_load_lds((GU*)(unsigned long long)g,
                                     (LU*)(unsigned int)(unsigned long long)l,
                                     16, 0, 0);
}

// ---------------- K0: fused fp32 -> bf16 convert (x, w_qkv, w_o) ----------
__global__ void cvt3_kernel(const float* __restrict__ x,
                            const float* __restrict__ wqkv,
                            const float* __restrict__ wo,
                            unsigned short* __restrict__ xb,
                            unsigned short* __restrict__ wqkvb,
                            unsigned short* __restrict__ wob) {
    int i = blockIdx.x * 256 + threadIdx.x;
    const float* src;
    unsigned short* dst;
    int off;
    if (i < 1048576) { src = x; dst = xb; off = i; }
    else if (i < 1835008) { src = wqkv; dst = wqkvb; off = i - 1048576; }
    else { src = wo; dst = wob; off = i - 1835008; }
    float4 f = ((const float4*)src)[off];
    u16x4 o;
    o[0] = f2bf(f.x); o[1] = f2bf(f.y); o[2] = f2bf(f.z); o[3] = f2bf(f.w);
    ((u16x4*)dst)[off] = o;
}

// ---------------- K1: qkv GEMM + fused rmsnorm/rope/pack epilogue ----------
// R3: 128x128xBK64 single-buffer (m97 structure), 3 blocks/CU, XOR swizzle.
#define TBS 72
__global__ __launch_bounds__(256, 3) void gemm_qkv(
    const unsigned short* __restrict__ A,    // xb [4096][1024]
    const unsigned short* __restrict__ Bt,   // wqkvb [3072][1024]
    const float* __restrict__ cosb, const float* __restrict__ sinb,  // [T][16]
    const float* __restrict__ qw, const float* __restrict__ kw,      // [64]
    unsigned short* __restrict__ Qb,  // [H][T][64] (pre-scaled)
    unsigned short* __restrict__ Kb,  // [H][T][64]
    unsigned short* __restrict__ Vt)  // [H][64][T] (pre-scaled by 0.5)
{
    __shared__ unsigned short smem[16384];  // 32 KB
    unsigned short* As0 = smem;             // [128][32]
    unsigned short* As1 = smem + 4096;
    unsigned short* Bs0 = smem + 8192;
    unsigned short* Bs1 = smem + 12288;

    const int tid = threadIdx.x;
    const int wave = tid >> 6, lane = tid & 63;
    const int quad = lane >> 4, l16 = lane & 15;
    const int m0 = blockIdx.x * 128, n0 = blockIdx.y * 128;
    const int wm = (wave >> 1) * 64, wn = (wave & 1) * 64;

    f32x4 acc[4][4];
#pragma unroll
    for (int i = 0; i < 4; ++i)
#pragma unroll
        for (int j = 0; j < 4; ++j) acc[i][j] = (f32x4){0.f, 0.f, 0.f, 0.f};

    const int lrow = lane >> 2;
    const int lcol = ((lane & 3) ^ ((lane >> 3) & 3)) * 8;   // swizzled src chunk
    const int csw  = (quad ^ ((l16 >> 1) & 3)) * 8;          // swizzled read chunk

    for (int k0 = 0; k0 < 1024; k0 += 64) {
        {
            const unsigned short* ab = A + (size_t)(m0 + wave * 16 + lrow) * 1024 + k0 + lcol;
            gl_lds16(ab,              &As0[wave * 512]);
            gl_lds16(ab + 32,         &As1[wave * 512]);
            gl_lds16(ab + 65536,      &As0[2048 + wave * 512]);   // rows +64
            gl_lds16(ab + 65536 + 32, &As1[2048 + wave * 512]);
            const unsigned short* bb = Bt + (size_t)(n0 + wave * 16 + lrow) * 1024 + k0 + lcol;
            gl_lds16(bb,              &Bs0[wave * 512]);
            gl_lds16(bb + 32,         &Bs1[wave * 512]);
            gl_lds16(bb + 65536,      &Bs0[2048 + wave * 512]);
            gl_lds16(bb + 65536 + 32, &Bs1[2048 + wave * 512]);
        }
        __syncthreads();
        {
            bf16x8 af[4], bfr[4];
#pragma unroll
            for (int mt = 0; mt < 4; ++mt)
                af[mt] = *(const bf16x8*)&As0[(wm + mt * 16 + l16) * 32 + csw];
#pragma unroll
            for (int nt = 0; nt < 4; ++nt)
                bfr[nt] = *(const bf16x8*)&Bs0[(wn + nt * 16 + l16) * 32 + csw];
#pragma unroll
            for (int mt = 0; mt < 4; ++mt)
#pragma unroll
                for (int nt = 0; nt < 4; ++nt)
                    acc[mt][nt] = MFMA16(af[mt], bfr[nt], acc[mt][nt]);
        }
        {
            bf16x8 af[4], bfr[4];
#pragma unroll
            for (int mt = 0; mt < 4; ++mt)
                af[mt] = *(const bf16x8*)&As1[(wm + mt * 16 + l16) * 32 + csw];
#pragma unroll
            for (int nt = 0; nt < 4; ++nt)
                bfr[nt] = *(const bf16x8*)&Bs1[(wn + nt * 16 + l16) * 32 + csw];
#pragma unroll
            for (int mt = 0; mt < 4; ++mt)
#pragma unroll
                for (int nt = 0; nt < 4; ++nt)
                    acc[mt][nt] = MFMA16(af[mt], bfr[nt], acc[mt][nt]);
        }
        __syncthreads();
    }

    unsigned short* tbw = smem + wave * 1152;
    const int region = blockIdx.y >> 3;
    const int h = ((blockIdx.y & 7) << 1) + (wave & 1);

    if (region < 2) {
        const float* wgt = region ? kw : qw;
        unsigned short* dst = region ? Kb : Qb;
        const float post = region ? 1.f : 0.17312340490667046f;
        float w[4];
#pragma unroll
        for (int nt = 0; nt < 4; ++nt) w[nt] = wgt[nt * 16 + l16] * post;
#pragma unroll
        for (int mt = 0; mt < 4; ++mt) {
#pragma unroll
            for (int r = 0; r < 4; ++r) {
                const int row = m0 + wm + mt * 16 + quad * 4 + r;
                float ss = 0.f;
#pragma unroll
                for (int nt = 0; nt < 4; ++nt)
                    ss += acc[mt][nt][r] * acc[mt][nt][r];
                ss += __shfl_xor(ss, 1); ss += __shfl_xor(ss, 2);
                ss += __shfl_xor(ss, 4); ss += __shfl_xor(ss, 8);
                const float rn = rsqrtf(ss * (1.f / 64.f) + 1e-6f);
                float val[4];
#pragma unroll
                for (int nt = 0; nt < 4; ++nt)
                    val[nt] = acc[mt][nt][r] * rn * w[nt];
#pragma unroll
                for (int nt = 0; nt < 2; ++nt) {
                    const float prt = __shfl_xor(val[nt], 1);
                    const int p = nt * 8 + (l16 >> 1);
                    const float c = cosb[row * 16 + p];
                    const float s = sinb[row * 16 + p];
                    val[nt] = (l16 & 1) ? (prt * s + val[nt] * c)
                                        : (val[nt] * c - prt * s);
                }
#pragma unroll
                for (int nt = 0; nt < 4; ++nt)
                    tbw[(quad * 4 + r) * TBS + nt * 16 + l16] = f2bf(val[nt]);
            }
            const int t = lane >> 2, dcol = (lane & 3) * 16;
            u16x8 v0 = *(const u16x8*)&tbw[t * TBS + dcol];
            u16x8 v1 = *(const u16x8*)&tbw[t * TBS + dcol + 8];
            const size_t ob = ((size_t)h * 4096 + (m0 + wm + mt * 16 + t)) * 64 + dcol;
            *(u16x8*)&dst[ob] = v0;
            *(u16x8*)&dst[ob + 8] = v1;
        }
    } else {
#pragma unroll
        for (int mt = 0; mt < 4; ++mt) {
#pragma unroll
            for (int nt = 0; nt < 4; ++nt)
#pragma unroll
                for (int r = 0; r < 4; ++r)
                    tbw[(nt * 16 + l16) * 16 + quad * 4 + r] =
                        f2bf(acc[mt][nt][r] * 0.5f);
            u16x8 v0 = *(const u16x8*)&tbw[lane * 16];
            u16x8 v1 = *(const u16x8*)&tbw[lane * 16 + 8];
            const size_t vo = ((size_t)h * 64 + lane) * 4096 + m0 + wm + mt * 16;
            *(u16x8*)&Vt[vo] = v0;
            *(u16x8*)&Vt[vo + 8] = v1;
        }
    }
}

// ---------------- K2: sliding-window flash attention ----------------------
// R3: 8 waves / 128 queries per block (staging amortized 8x), dbuf K/V,
// prefetch-before-compute, 1 barrier/step, XOR swizzle, per-wave dead-tile
// skip, unified unsigned-window mask. LDS 50KB; 512 blocks = 2/CU.
#define PSTR 72  // P row stride (>=64 required; 144 B, 16B-aligned)

template <int MASK>
__device__ __forceinline__ void attn_compute(
    int s0, int tq, int quad, int l16, int csw,
    const unsigned short* Ks0, const unsigned short* Ks1,
    const unsigned short* Vs0, const unsigned short* Vs1,
    unsigned short* Pw, const bf16x8 qf0, const bf16x8 qf1,
    f32x4 (&o)[4], float& lsum)
{
#pragma unroll
    for (int i = 0; i < 4; ++i) {
        // Z_i = K_i * Q^T: A-frag = K rows (contiguous d); C: row=key col=query
        const bf16x8 kf0 = *(const bf16x8*)&Ks0[(i * 16 + l16) * 32 + csw];
        const bf16x8 kf1 = *(const bf16x8*)&Ks1[(i * 16 + l16) * 32 + csw];
        f32x4 z = (f32x4){0.f, 0.f, 0.f, 0.f};
        z = MFMA16(kf0, qf0, z);
        z = MFMA16(kf1, qf1, z);
        float p[4];
#pragma unroll
        for (int r = 0; r < 4; ++r) {
            float e = fexp2(z[r]);   // scale pre-folded into Q
            if (MASK) {              // causal + window in one unsigned compare
                const int s = s0 + i * 16 + quad * 4 + r;
                e = ((unsigned)(tq - s) < 1024u) ? e : 0.f;
            }
            p[r] = e;
            lsum += e;
        }
        uint2 pk;
        pk.x = pk2bf(p[0], p[1]);
        pk.y = pk2bf(p[2], p[3]);
        *(uint2*)&Pw[l16 * PSTR + i * 16 + quad * 4] = pk;
    }
    // P read (A-operand) — wave-private, lgkmcnt ordering suffices
    const bf16x8 pf0 = *(const bf16x8*)&Pw[l16 * PSTR + quad * 8];
    const bf16x8 pf1 = *(const bf16x8*)&Pw[l16 * PSTR + 32 + quad * 8];
#pragma unroll
    for (int dt = 0; dt < 4; ++dt) {
        const bf16x8 vf0 = *(const bf16x8*)&Vs0[(dt * 16 + l16) * 32 + csw];
        const bf16x8 vf1 = *(const bf16x8*)&Vs1[(dt * 16 + l16) * 32 + csw];
        o[dt] = MFMA16(pf0, vf0, o[dt]);
        o[dt] = MFMA16(pf1, vf1, o[dt]);
    }
}

__global__ __launch_bounds__(512, 4) void attn_kernel(
    const unsigned short* __restrict__ Qb,  // [H][T][64] (pre-scaled)
    const unsigned short* __restrict__ Kb,  // [H][T][64]
    const unsigned short* __restrict__ Vt,  // [H][64][T] (pre-scaled by 0.5)
    unsigned short* __restrict__ att)       // [T][1024]
{
    __shared__ unsigned short Ks0[2][2048], Ks1[2][2048];
    __shared__ unsigned short Vs0[2][2048], Vs1[2][2048];
    __shared__ unsigned short P[8][16 * PSTR];

    // swizzle: h-pair = bid&7 (XCD locality); t descending (LPT balance)
    const int bid = blockIdx.x;
    const int h = ((bid & 7) << 1) | ((bid >> 3) & 1);
    const int t0 = (31 - (bid >> 4)) * 128;

    const int tid = threadIdx.x;
    const int wave = tid >> 6, lane = tid & 63;
    const int quad = lane >> 4, l16 = lane & 15;
    const int qt0 = t0 + wave * 16;
    const int tq = qt0 + l16;        // this lane's query (S^T col)
    // staging: waves 0-3 stage K, waves 4-7 stage V (2 gl_lds each)
    const int srow = (tid & 255) >> 2;
    const int scol = ((tid & 3) ^ ((tid >> 3) & 3)) * 8;   // swizzled src chunk
    const int csw  = (quad ^ ((l16 >> 1) & 3)) * 8;        // swizzled read chunk

    const unsigned short* Qh = Qb + (size_t)h * 4096 * 64;
    const unsigned short* Kh = Kb + (size_t)h * 4096 * 64;
    const unsigned short* Vh = Vt + (size_t)h * 64 * 4096;

    const bf16x8 qf0 = *(const bf16x8*)&Qh[(qt0 + l16) * 64 + quad * 8];
    const bf16x8 qf1 = *(const bf16x8*)&Qh[(qt0 + l16) * 64 + 32 + quad * 8];

    f32x4 o[4];
#pragma unroll
    for (int dt = 0; dt < 4; ++dt) o[dt] = (f32x4){0.f, 0.f, 0.f, 0.f};
    float lsum = 0.f;
    unsigned short* Pw = P[wave];

    auto stage = [&](int b, int s0) {
        if (wave < 4) {
            const unsigned short* kb = Kh + (size_t)(s0 + srow) * 64 + scol;
            gl_lds16(kb,      &Ks0[b][wave * 512]);
            gl_lds16(kb + 32, &Ks1[b][wave * 512]);
        } else {
            const unsigned short* vb = Vh + (size_t)srow * 4096 + s0 + scol;
            gl_lds16(vb,      &Vs0[b][(wave - 4) * 512]);
            gl_lds16(vb + 32, &Vs1[b][(wave - 4) * 512]);
        }
    };

    const int s_lo = (t0 >= 1024) ? (t0 - 1024) : 0;
    const int s_hi = t0 + 64;      // last tile start (covers keys to t0+127)
    stage(0, s_lo);
    __syncthreads();               // vmcnt(0) drained by barrier
    int buf = 0;
    for (int s0 = s_lo; s0 <= s_hi; s0 += 64) {
        if (s0 < s_hi) stage(buf ^ 1, s0 + 64);   // prefetch before compute
        // per-wave tile classification (wave-uniform branches)
        const bool dead = (s0 > qt0 + 15) || (s0 + 63 < qt0 - 1023);
        if (!dead) {
            const bool clean = (s0 + 63 <= qt0) && (s0 >= qt0 - 1008);
            if (clean)
                attn_compute<0>(s0, tq, quad, l16, csw, Ks0[buf], Ks1[buf],
                                Vs0[buf], Vs1[buf], Pw, qf0, qf1, o, lsum);
            else
                attn_compute<1>(s0, tq, quad, l16, csw, Ks0[buf], Ks1[buf],
                                Vs0[buf], Vs1[buf], Pw, qf0, qf1, o, lsum);
        }
        __syncthreads();           // prefetch landed + all waves done reading
        buf ^= 1;
    }

    lsum += __shfl_xor(lsum, 16);
    lsum += __shfl_xor(lsum, 32);
    float lr[4];
#pragma unroll
    for (int r = 0; r < 4; ++r) lr[r] = 1.f / __shfl(lsum, quad * 4 + r);
#pragma unroll
    for (int dt = 0; dt < 4; ++dt)
#pragma unroll
        for (int r = 0; r < 4; ++r)
            att[(size_t)(qt0 + quad * 4 + r) * 1024 + h * 64 + dt * 16 + l16] =
                f2bf(o[dt][r] * lr[r]);
}

// ---------------- K3: output GEMM (BM=64, BN=128, BK=64, prefetch-dbuf) ---
// Session-measured-best config (512 blocks, 2/CU supply-starved regime:
// dbuf is the measured win there). + R2 XOR bank-swizzle.
__global__ __launch_bounds__(256) void gemm_out(
    const unsigned short* __restrict__ A,    // attb [4096][1024]
    const unsigned short* __restrict__ Bt,   // wob  [1024][1024]
    float* __restrict__ C)                   // [4096][1024]
{
    __shared__ unsigned short As0[2][2048], As1[2][2048];
    __shared__ unsigned short Bs0[2][4096], Bs1[2][4096];
    const int tid = threadIdx.x;
    const int wave = tid >> 6, lane = tid & 63;
    const int quad = lane >> 4, l16 = lane & 15;
    const int m0 = blockIdx.x * 64, n0 = blockIdx.y * 128;
    const int wm = (wave >> 1) * 32, wn = (wave & 1) * 64;
    const int lrow = lane >> 2;
    const int lcol = ((lane & 3) ^ ((lane >> 3) & 3)) * 8;   // swizzled src chunk
    const int csw  = (quad ^ ((l16 >> 1) & 3)) * 8;          // swizzled read chunk

    f32x4 acc[2][4];
#pragma unroll
    for (int i = 0; i < 2; ++i)
#pragma unroll
        for (int j = 0; j < 4; ++j) acc[i][j] = (f32x4){0.f, 0.f, 0.f, 0.f};

    auto stage = [&](int buf, int k0) {
        const unsigned short* ab = A + (size_t)(m0 + wave * 16 + lrow) * 1024 + k0 + lcol;
        gl_lds16(ab,      &As0[buf][wave * 512]);
        gl_lds16(ab + 32, &As1[buf][wave * 512]);
#pragma unroll
        for (int i = 0; i < 2; ++i) {
            const int c = wave * 2 + i;
            const unsigned short* bb = Bt + (size_t)(n0 + c * 16 + lrow) * 1024 + k0 + lcol;
            gl_lds16(bb,      &Bs0[buf][c * 512]);
            gl_lds16(bb + 32, &Bs1[buf][c * 512]);
        }
    };

    stage(0, 0);
    __syncthreads();
    int buf = 0;
    for (int k0 = 0; k0 < 1024; k0 += 64) {
        if (k0 + 64 < 1024) stage(buf ^ 1, k0 + 64);  // prefetch before compute
        {
            bf16x8 af[2], bfr[4];
#pragma unroll
            for (int mt = 0; mt < 2; ++mt)
                af[mt] = *(const bf16x8*)&As0[buf][(wm + mt * 16 + l16) * 32 + csw];
#pragma unroll
            for (int nt = 0; nt < 4; ++nt)
                bfr[nt] = *(const bf16x8*)&Bs0[buf][(wn + nt * 16 + l16) * 32 + csw];
#pragma unroll
            for (int mt = 0; mt < 2; ++mt)
#pragma unroll
                for (int nt = 0; nt < 4; ++nt)
                    acc[mt][nt] = MFMA16(af[mt], bfr[nt], acc[mt][nt]);
        }
        {
            bf16x8 af[2], bfr[4];
#pragma unroll
            for (int mt = 0; mt < 2; ++mt)
                af[mt] = *(const bf16x8*)&As1[buf][(wm + mt * 16 + l16) * 32 + csw];
#pragma unroll
            for (int nt = 0; nt < 4; ++nt)
                bfr[nt] = *(const bf16x8*)&Bs1[buf][(wn + nt * 16 + l16) * 32 + csw];
#pragma unroll
            for (int mt = 0; mt < 2; ++mt)
#pragma unroll
                for (int nt = 0; nt < 4; ++nt)
                    acc[mt][nt] = MFMA16(af[mt], bfr[nt], acc[mt][nt]);
        }
        __syncthreads();  // publishes prefetched tiles; protects buf reuse
        buf ^= 1;
    }
#pragma unroll
    for (int mt = 0; mt < 2; ++mt)
#pragma unroll
        for (int nt = 0; nt < 4; ++nt)
#pragma unroll
            for (int r = 0; r < 4; ++r) {
                const int row = m0 + wm + mt * 16 + quad * 4 + r;
                const int col = n0 + wn + nt * 16 + l16;
                C[(size_t)row * 1024 + col] = acc[mt][nt][r];
            }
}

// ---------------- launcher ----------------
extern "C" void kernel_launch(void* const* d_in, const int* in_sizes, int n_in,
                              void* d_out, int out_size, void* d_ws, size_t ws_size,
                              hipStream_t stream) {
    const float* x    = (const float*)d_in[0];
    const float* wqkv = (const float*)d_in[3];
    const float* wo   = (const float*)d_in[4];
    const float* qw   = (const float*)d_in[5];
    const float* kw   = (const float*)d_in[6];
    const float* cosb = (const float*)d_in[7];
    const float* sinb = (const float*)d_in[8];

    char* ws = (char*)d_ws;
    // ws (MiB): xb 0-8 | wqkvb 8-14 | wob 14-16 | Qb 16-24 | Kb 24-32
    //           Vt 32-40 | attb 40-48
    if (ws_size < (size_t)48 * 1024 * 1024) return;
    unsigned short* xb    = (unsigned short*)(ws + ((size_t)0 << 20));
    unsigned short* wqkvb = (unsigned short*)(ws + ((size_t)8 << 20));
    unsigned short* wob   = (unsigned short*)(ws + ((size_t)14 << 20));
    unsigned short* Qb    = (unsigned short*)(ws + ((size_t)16 << 20));
    unsigned short* Kb    = (unsigned short*)(ws + ((size_t)24 << 20));
    unsigned short* Vt    = (unsigned short*)(ws + ((size_t)32 << 20));
    unsigned short* attb  = (unsigned short*)(ws + ((size_t)40 << 20));

    // K0: fused converts (one launch)
    cvt3_kernel<<<8192, 256, 0, stream>>>(x, wqkv, wo, xb, wqkvb, wob);

    // K1: qkv GEMM + fused rmsnorm/rope/pack epilogue (128x128x64, 3/CU)
    gemm_qkv<<<dim3(32, 24), 256, 0, stream>>>(xb, wqkvb, cosb, sinb, qw, kw,
                                               Qb, Kb, Vt);

    // K2: sliding-window attention (8-wave/128q blocks, dbuf K/V + swizzle)
    attn_kernel<<<512, 512, 0, stream>>>(Qb, Kb, Vt, attb);

    // K3: y = att @ w_o^T  (M=4096, N=1024, K=1024), fp32 out, BK64 dbuf
    gemm_out<<<dim3(64, 8), 256, 0, stream>>>(attb, wob, (float*)d_out);
}

// Round 4
// 177.098 us; speedup vs baseline: 1.0547x; 1.0048x over previous
//
#include <hip/hip_runtime.h>

// Problem constants (hardcoded from reference):
//   T=4096, D_MODEL=1024, N_HEADS=16, HEAD_DIM=64, ROT=32, PAIR=16,
//   EPS=1e-6, SCALE=0.12, WINDOW=1024. tokens/pos/block_size unused.
//
// Attention numerics: rmsnorm => ||q||=||k||=8, so |q.k|*SCALE <= 7.68 ->
// exp bounded [4.6e-4, 2164]: softmax max-subtraction unnecessary.
// SCALE*log2(e) pre-folded into Q at the gemm_qkv epilogue: p = exp2(z).
//
// R4 changes (attn only; clean attribution):
//  - 128-key tiles, 9 steps (was 18), 2 barriers/step (18 total, unchanged):
//    stage K(n+1)+V(n) under QK phase -> barrier -> PV(h0) -> QK(h1) -> PV(h1)
//    -> barrier. V single-buffered (staged one phase ahead of use); K dbuf.
//    h1-QK MFMA stream is independent of PV(h0)'s P-chain -> scheduler can
//    overlap; V latency hidden under full QK phase.
//  - per-half dead/clean classification (wave-uniform) preserved.
//  - s_setprio(1) around PV MFMA cluster (T5, measured +4-7% attn).
//  - LDS 66KB -> 2 blocks/CU unchanged.

typedef __bf16 bf16x8 __attribute__((ext_vector_type(8)));
typedef __bf16 bf16x2 __attribute__((ext_vector_type(2)));
typedef float f32x4 __attribute__((ext_vector_type(4)));
typedef unsigned short u16x8 __attribute__((ext_vector_type(8)));
typedef unsigned short u16x4 __attribute__((ext_vector_type(4)));

#define MFMA16(a, b, c) __builtin_amdgcn_mfma_f32_16x16x32_bf16((a), (b), (c), 0, 0, 0)

__device__ __forceinline__ unsigned short f2bf(float f) {
    unsigned int u = __float_as_uint(f);
    u += 0x7fffu + ((u >> 16) & 1u);   // round-to-nearest-even
    return (unsigned short)(u >> 16);
}
__device__ __forceinline__ float bf2f(unsigned short h) {
    return __uint_as_float(((unsigned int)h) << 16);
}
__device__ __forceinline__ unsigned int pk2bf(float a, float b) {
#if __has_builtin(__builtin_amdgcn_cvt_pk_bf16_f32)
    bf16x2 v = __builtin_amdgcn_cvt_pk_bf16_f32(a, b);
    return __builtin_bit_cast(unsigned int, v);
#else
    return (unsigned int)f2bf(a) | ((unsigned int)f2bf(b) << 16);
#endif
}
__device__ __forceinline__ float fexp2(float x) {
#if __has_builtin(__builtin_amdgcn_exp2f)
    return __builtin_amdgcn_exp2f(x);   // raw v_exp_f32; args bounded +-1.33
#else
    return exp2f(x);
#endif
}

// async global->LDS, 16B per lane; LDS dest = wave-uniform base + lane*16
__device__ __forceinline__ void gl_lds16(const void* g, void* l) {
    typedef __attribute__((address_space(1))) unsigned int GU;
    typedef __attribute__((address_space(3))) unsigned int LU;
    __builtin_amdgcn_global_load_lds((GU*)(unsigned long long)g,
                                     (LU*)(unsigned int)(unsigned long long)l,
                                     16, 0, 0);
}

// ---------------- K0: fused fp32 -> bf16 convert (x, w_qkv, w_o) ----------
__global__ void cvt3_kernel(const float* __restrict__ x,
                            const float* __restrict__ wqkv,
                            const float* __restrict__ wo,
                            unsigned short* __restrict__ xb,
                            unsigned short* __restrict__ wqkvb,
                            unsigned short* __restrict__ wob) {
    int i = blockIdx.x * 256 + threadIdx.x;
    const float* src;
    unsigned short* dst;
    int off;
    if (i < 1048576) { src = x; dst = xb; off = i; }
    else if (i < 1835008) { src = wqkv; dst = wqkvb; off = i - 1048576; }
    else { src = wo; dst = wob; off = i - 1835008; }
    float4 f = ((const float4*)src)[off];
    u16x4 o;
    o[0] = f2bf(f.x); o[1] = f2bf(f.y); o[2] = f2bf(f.z); o[3] = f2bf(f.w);
    ((u16x4*)dst)[off] = o;
}

// ---------------- K1: qkv GEMM + fused rmsnorm/rope/pack epilogue ----------
// R3 config: 128x128xBK64 single-buffer (m97 structure), 3/CU, XOR swizzle.
#define TBS 72
__global__ __launch_bounds__(256, 3) void gemm_qkv(
    const unsigned short* __restrict__ A,    // xb [4096][1024]
    const unsigned short* __restrict__ Bt,   // wqkvb [3072][1024]
    const float* __restrict__ cosb, const float* __restrict__ sinb,  // [T][16]
    const float* __restrict__ qw, const float* __restrict__ kw,      // [64]
    unsigned short* __restrict__ Qb,  // [H][T][64] (pre-scaled)
    unsigned short* __restrict__ Kb,  // [H][T][64]
    unsigned short* __restrict__ Vt)  // [H][64][T] (pre-scaled by 0.5)
{
    __shared__ unsigned short smem[16384];  // 32 KB
    unsigned short* As0 = smem;             // [128][32]
    unsigned short* As1 = smem + 4096;
    unsigned short* Bs0 = smem + 8192;
    unsigned short* Bs1 = smem + 12288;

    const int tid = threadIdx.x;
    const int wave = tid >> 6, lane = tid & 63;
    const int quad = lane >> 4, l16 = lane & 15;
    const int m0 = blockIdx.x * 128, n0 = blockIdx.y * 128;
    const int wm = (wave >> 1) * 64, wn = (wave & 1) * 64;

    f32x4 acc[4][4];
#pragma unroll
    for (int i = 0; i < 4; ++i)
#pragma unroll
        for (int j = 0; j < 4; ++j) acc[i][j] = (f32x4){0.f, 0.f, 0.f, 0.f};

    const int lrow = lane >> 2;
    const int lcol = ((lane & 3) ^ ((lane >> 3) & 3)) * 8;   // swizzled src chunk
    const int csw  = (quad ^ ((l16 >> 1) & 3)) * 8;          // swizzled read chunk

    for (int k0 = 0; k0 < 1024; k0 += 64) {
        {
            const unsigned short* ab = A + (size_t)(m0 + wave * 16 + lrow) * 1024 + k0 + lcol;
            gl_lds16(ab,              &As0[wave * 512]);
            gl_lds16(ab + 32,         &As1[wave * 512]);
            gl_lds16(ab + 65536,      &As0[2048 + wave * 512]);   // rows +64
            gl_lds16(ab + 65536 + 32, &As1[2048 + wave * 512]);
            const unsigned short* bb = Bt + (size_t)(n0 + wave * 16 + lrow) * 1024 + k0 + lcol;
            gl_lds16(bb,              &Bs0[wave * 512]);
            gl_lds16(bb + 32,         &Bs1[wave * 512]);
            gl_lds16(bb + 65536,      &Bs0[2048 + wave * 512]);
            gl_lds16(bb + 65536 + 32, &Bs1[2048 + wave * 512]);
        }
        __syncthreads();
        {
            bf16x8 af[4], bfr[4];
#pragma unroll
            for (int mt = 0; mt < 4; ++mt)
                af[mt] = *(const bf16x8*)&As0[(wm + mt * 16 + l16) * 32 + csw];
#pragma unroll
            for (int nt = 0; nt < 4; ++nt)
                bfr[nt] = *(const bf16x8*)&Bs0[(wn + nt * 16 + l16) * 32 + csw];
#pragma unroll
            for (int mt = 0; mt < 4; ++mt)
#pragma unroll
                for (int nt = 0; nt < 4; ++nt)
                    acc[mt][nt] = MFMA16(af[mt], bfr[nt], acc[mt][nt]);
        }
        {
            bf16x8 af[4], bfr[4];
#pragma unroll
            for (int mt = 0; mt < 4; ++mt)
                af[mt] = *(const bf16x8*)&As1[(wm + mt * 16 + l16) * 32 + csw];
#pragma unroll
            for (int nt = 0; nt < 4; ++nt)
                bfr[nt] = *(const bf16x8*)&Bs1[(wn + nt * 16 + l16) * 32 + csw];
#pragma unroll
            for (int mt = 0; mt < 4; ++mt)
#pragma unroll
                for (int nt = 0; nt < 4; ++nt)
                    acc[mt][nt] = MFMA16(af[mt], bfr[nt], acc[mt][nt]);
        }
        __syncthreads();
    }

    unsigned short* tbw = smem + wave * 1152;
    const int region = blockIdx.y >> 3;
    const int h = ((blockIdx.y & 7) << 1) + (wave & 1);

    if (region < 2) {
        const float* wgt = region ? kw : qw;
        unsigned short* dst = region ? Kb : Qb;
        const float post = region ? 1.f : 0.17312340490667046f;
        float w[4];
#pragma unroll
        for (int nt = 0; nt < 4; ++nt) w[nt] = wgt[nt * 16 + l16] * post;
#pragma unroll
        for (int mt = 0; mt < 4; ++mt) {
#pragma unroll
            for (int r = 0; r < 4; ++r) {
                const int row = m0 + wm + mt * 16 + quad * 4 + r;
                float ss = 0.f;
#pragma unroll
                for (int nt = 0; nt < 4; ++nt)
                    ss += acc[mt][nt][r] * acc[mt][nt][r];
                ss += __shfl_xor(ss, 1); ss += __shfl_xor(ss, 2);
                ss += __shfl_xor(ss, 4); ss += __shfl_xor(ss, 8);
                const float rn = rsqrtf(ss * (1.f / 64.f) + 1e-6f);
                float val[4];
#pragma unroll
                for (int nt = 0; nt < 4; ++nt)
                    val[nt] = acc[mt][nt][r] * rn * w[nt];
#pragma unroll
                for (int nt = 0; nt < 2; ++nt) {
                    const float prt = __shfl_xor(val[nt], 1);
                    const int p = nt * 8 + (l16 >> 1);
                    const float c = cosb[row * 16 + p];
                    const float s = sinb[row * 16 + p];
                    val[nt] = (l16 & 1) ? (prt * s + val[nt] * c)
                                        : (val[nt] * c - prt * s);
                }
#pragma unroll
                for (int nt = 0; nt < 4; ++nt)
                    tbw[(quad * 4 + r) * TBS + nt * 16 + l16] = f2bf(val[nt]);
            }
            const int t = lane >> 2, dcol = (lane & 3) * 16;
            u16x8 v0 = *(const u16x8*)&tbw[t * TBS + dcol];
            u16x8 v1 = *(const u16x8*)&tbw[t * TBS + dcol + 8];
            const size_t ob = ((size_t)h * 4096 + (m0 + wm + mt * 16 + t)) * 64 + dcol;
            *(u16x8*)&dst[ob] = v0;
            *(u16x8*)&dst[ob + 8] = v1;
        }
    } else {
#pragma unroll
        for (int mt = 0; mt < 4; ++mt) {
#pragma unroll
            for (int nt = 0; nt < 4; ++nt)
#pragma unroll
                for (int r = 0; r < 4; ++r)
                    tbw[(nt * 16 + l16) * 16 + quad * 4 + r] =
                        f2bf(acc[mt][nt][r] * 0.5f);
            u16x8 v0 = *(const u16x8*)&tbw[lane * 16];
            u16x8 v1 = *(const u16x8*)&tbw[lane * 16 + 8];
            const size_t vo = ((size_t)h * 64 + lane) * 4096 + m0 + wm + mt * 16;
            *(u16x8*)&Vt[vo] = v0;
            *(u16x8*)&Vt[vo + 8] = v1;
        }
    }
}

// ---------------- K2: sliding-window flash attention ----------------------
// R4: 128-key tiles, K dbuf + V single-buffer staged one phase early,
// 2 barriers/tile, per-half dead/clean skip, setprio around PV MFMA.
// 8 waves / 128 queries per block. LDS 66KB -> 2 blocks/CU.
#define PSTR 72  // P row stride (>=64 required; 144 B, 16B-aligned)

template <int MASK>
__device__ __forceinline__ void qk_exp(
    int sb, int tq, int quad, int l16, int csw, int rbase,
    const unsigned short* KsA, const unsigned short* KsB,
    unsigned short* Pw, const bf16x8 qf0, const bf16x8 qf1, float& lsum)
{
#pragma unroll
    for (int i = 0; i < 4; ++i) {
        // Z_i = K_i * Q^T: A-frag = K rows (contiguous d); C: row=key col=query
        const bf16x8 kf0 = *(const bf16x8*)&KsA[(rbase + i * 16 + l16) * 32 + csw];
        const bf16x8 kf1 = *(const bf16x8*)&KsB[(rbase + i * 16 + l16) * 32 + csw];
        f32x4 z = (f32x4){0.f, 0.f, 0.f, 0.f};
        z = MFMA16(kf0, qf0, z);
        z = MFMA16(kf1, qf1, z);
        float p[4];
#pragma unroll
        for (int r = 0; r < 4; ++r) {
            float e = fexp2(z[r]);   // scale pre-folded into Q
            if (MASK) {              // causal + window in one unsigned compare
                const int s = sb + i * 16 + quad * 4 + r;
                e = ((unsigned)(tq - s) < 1024u) ? e : 0.f;
            }
            p[r] = e;
            lsum += e;
        }
        uint2 pk;
        pk.x = pk2bf(p[0], p[1]);
        pk.y = pk2bf(p[2], p[3]);
        *(uint2*)&Pw[l16 * PSTR + i * 16 + quad * 4] = pk;
    }
}

__device__ __forceinline__ void pv_acc(
    int quad, int l16, int csw,
    const unsigned short* VsA, const unsigned short* VsB,
    const unsigned short* Pw, f32x4 (&o)[4])
{
    // P read (A-operand) — wave-private, in-order LDS + lgkmcnt suffices
    const bf16x8 pf0 = *(const bf16x8*)&Pw[l16 * PSTR + quad * 8];
    const bf16x8 pf1 = *(const bf16x8*)&Pw[l16 * PSTR + 32 + quad * 8];
    __builtin_amdgcn_s_setprio(1);
#pragma unroll
    for (int dt = 0; dt < 4; ++dt) {
        const bf16x8 vf0 = *(const bf16x8*)&VsA[(dt * 16 + l16) * 32 + csw];
        const bf16x8 vf1 = *(const bf16x8*)&VsB[(dt * 16 + l16) * 32 + csw];
        o[dt] = MFMA16(pf0, vf0, o[dt]);
        o[dt] = MFMA16(pf1, vf1, o[dt]);
    }
    __builtin_amdgcn_s_setprio(0);
}

__global__ __launch_bounds__(512, 4) void attn_kernel(
    const unsigned short* __restrict__ Qb,  // [H][T][64] (pre-scaled)
    const unsigned short* __restrict__ Kb,  // [H][T][64]
    const unsigned short* __restrict__ Vt,  // [H][64][T] (pre-scaled by 0.5)
    unsigned short* __restrict__ att)       // [T][1024]
{
    __shared__ unsigned short KsA[2][4096], KsB[2][4096];   // [128 keys][32 d]
    __shared__ unsigned short Vs0[2048], Vs1[2048];         // [64 d][32 t] (t 0-63)
    __shared__ unsigned short Vs2[2048], Vs3[2048];         // (t 64-127)
    __shared__ unsigned short P[8][16 * PSTR];

    // swizzle: h-pair = bid&7 (XCD locality); t descending (LPT balance)
    const int bid = blockIdx.x;
    const int h = ((bid & 7) << 1) | ((bid >> 3) & 1);
    const int t0 = (31 - (bid >> 4)) * 128;

    const int tid = threadIdx.x;
    const int wave = tid >> 6, lane = tid & 63;
    const int quad = lane >> 4, l16 = lane & 15;
    const int qt0 = t0 + wave * 16;
    const int tq = qt0 + l16;        // this lane's query (S^T col)
    // staging: waves 0-3 stage K (4 gl_lds), waves 4-7 stage V (4 gl_lds)
    const int srow = (tid & 255) >> 2;
    const int scol = ((tid & 3) ^ ((tid >> 3) & 3)) * 8;   // swizzled src chunk
    const int csw  = (quad ^ ((l16 >> 1) & 3)) * 8;        // swizzled read chunk

    const unsigned short* Qh = Qb + (size_t)h * 4096 * 64;
    const unsigned short* Kh = Kb + (size_t)h * 4096 * 64;
    const unsigned short* Vh = Vt + (size_t)h * 64 * 4096;

    const bf16x8 qf0 = *(const bf16x8*)&Qh[(qt0 + l16) * 64 + quad * 8];
    const bf16x8 qf1 = *(const bf16x8*)&Qh[(qt0 + l16) * 64 + 32 + quad * 8];

    f32x4 o[4];
#pragma unroll
    for (int dt = 0; dt < 4; ++dt) o[dt] = (f32x4){0.f, 0.f, 0.f, 0.f};
    float lsum = 0.f;
    unsigned short* Pw = P[wave];

    auto stageK = [&](int b, int s) {
        if (wave < 4) {
            const unsigned short* kb = Kh + (size_t)(s + srow) * 64 + scol;
            gl_lds16(kb,             &KsA[b][wave * 512]);
            gl_lds16(kb + 32,        &KsB[b][wave * 512]);
            gl_lds16(kb + 4096,      &KsA[b][2048 + wave * 512]);  // rows +64
            gl_lds16(kb + 4096 + 32, &KsB[b][2048 + wave * 512]);
        }
    };
    auto stageV = [&](int s) {
        if (wave >= 4) {
            const unsigned short* vb = Vh + (size_t)srow * 4096 + s + scol;
            gl_lds16(vb,      &Vs0[(wave - 4) * 512]);
            gl_lds16(vb + 32, &Vs1[(wave - 4) * 512]);
            gl_lds16(vb + 64, &Vs2[(wave - 4) * 512]);
            gl_lds16(vb + 96, &Vs3[(wave - 4) * 512]);
        }
    };

    const int s_lo = (t0 >= 1024) ? (t0 - 1024) : 0;
    const int NT = ((t0 - s_lo) >> 7) + 1;   // 128-key tiles

    stageK(0, s_lo);
    __syncthreads();               // K(0) landed (vmcnt drained by barrier)
    int buf = 0;
    for (int n = 0; n < NT; ++n) {
        const int s0 = s_lo + n * 128;
        const int sb1 = s0 + 64;
        if (n + 1 < NT) stageK(buf ^ 1, s0 + 128);   // issue under QK phase
        stageV(s0);                                  // consumed after barrier
        // per-half, per-wave classification (wave-uniform branches)
        const bool d0 = (s0 + 63 < qt0 - 1023);      // h0 never future-dead
        const bool c0 = (s0 + 63 <= qt0) && (s0 >= qt0 - 1008);
        const bool d1 = (sb1 > qt0 + 15) || (sb1 + 63 < qt0 - 1023);
        const bool c1 = (sb1 + 63 <= qt0) && (sb1 >= qt0 - 1008);
        if (!d0) {
            if (c0) qk_exp<0>(s0, tq, quad, l16, csw, 0, KsA[buf], KsB[buf],
                              Pw, qf0, qf1, lsum);
            else    qk_exp<1>(s0, tq, quad, l16, csw, 0, KsA[buf], KsB[buf],
                              Pw, qf0, qf1, lsum);
        }
        __syncthreads();           // V(n) + K(n+1) landed; P(h0) wave-private
        if (!d0) pv_acc(quad, l16, csw, Vs0, Vs1, Pw, o);
        if (!d1) {
            if (c1) qk_exp<0>(sb1, tq, quad, l16, csw, 64, KsA[buf], KsB[buf],
                              Pw, qf0, qf1, lsum);
            else    qk_exp<1>(sb1, tq, quad, l16, csw, 64, KsA[buf], KsB[buf],
                              Pw, qf0, qf1, lsum);
            pv_acc(quad, l16, csw, Vs2, Vs3, Pw, o);
        }
        __syncthreads();           // all reads of Kb[buf]/Vs done before restage
        buf ^= 1;
    }

    lsum += __shfl_xor(lsum, 16);
    lsum += __shfl_xor(lsum, 32);
    float lr[4];
#pragma unroll
    for (int r = 0; r < 4; ++r) lr[r] = 1.f / __shfl(lsum, quad * 4 + r);
#pragma unroll
    for (int dt = 0; dt < 4; ++dt)
#pragma unroll
        for (int r = 0; r < 4; ++r)
            att[(size_t)(qt0 + quad * 4 + r) * 1024 + h * 64 + dt * 16 + l16] =
                f2bf(o[dt][r] * lr[r]);
}

// ---------------- K3: output GEMM (BM=64, BN=128, BK=64, prefetch-dbuf) ---
// Session-measured-best config (512 blocks, 2/CU supply-starved regime:
// dbuf is the measured win there). + R2 XOR bank-swizzle.
__global__ __launch_bounds__(256) void gemm_out(
    const unsigned short* __restrict__ A,    // attb [4096][1024]
    const unsigned short* __restrict__ Bt,   // wob  [1024][1024]
    float* __restrict__ C)                   // [4096][1024]
{
    __shared__ unsigned short As0[2][2048], As1[2][2048];
    __shared__ unsigned short Bs0[2][4096], Bs1[2][4096];
    const int tid = threadIdx.x;
    const int wave = tid >> 6, lane = tid & 63;
    const int quad = lane >> 4, l16 = lane & 15;
    const int m0 = blockIdx.x * 64, n0 = blockIdx.y * 128;
    const int wm = (wave >> 1) * 32, wn = (wave & 1) * 64;
    const int lrow = lane >> 2;
    const int lcol = ((lane & 3) ^ ((lane >> 3) & 3)) * 8;   // swizzled src chunk
    const int csw  = (quad ^ ((l16 >> 1) & 3)) * 8;          // swizzled read chunk

    f32x4 acc[2][4];
#pragma unroll
    for (int i = 0; i < 2; ++i)
#pragma unroll
        for (int j = 0; j < 4; ++j) acc[i][j] = (f32x4){0.f, 0.f, 0.f, 0.f};

    auto stage = [&](int buf, int k0) {
        const unsigned short* ab = A + (size_t)(m0 + wave * 16 + lrow) * 1024 + k0 + lcol;
        gl_lds16(ab,      &As0[buf][wave * 512]);
        gl_lds16(ab + 32, &As1[buf][wave * 512]);
#pragma unroll
        for (int i = 0; i < 2; ++i) {
            const int c = wave * 2 + i;
            const unsigned short* bb = Bt + (size_t)(n0 + c * 16 + lrow) * 1024 + k0 + lcol;
            gl_lds16(bb,      &Bs0[buf][c * 512]);
            gl_lds16(bb + 32, &Bs1[buf][c * 512]);
        }
    };

    stage(0, 0);
    __syncthreads();
    int buf = 0;
    for (int k0 = 0; k0 < 1024; k0 += 64) {
        if (k0 + 64 < 1024) stage(buf ^ 1, k0 + 64);  // prefetch before compute
        {
            bf16x8 af[2], bfr[4];
#pragma unroll
            for (int mt = 0; mt < 2; ++mt)
                af[mt] = *(const bf16x8*)&As0[buf][(wm + mt * 16 + l16) * 32 + csw];
#pragma unroll
            for (int nt = 0; nt < 4; ++nt)
                bfr[nt] = *(const bf16x8*)&Bs0[buf][(wn + nt * 16 + l16) * 32 + csw];
#pragma unroll
            for (int mt = 0; mt < 2; ++mt)
#pragma unroll
                for (int nt = 0; nt < 4; ++nt)
                    acc[mt][nt] = MFMA16(af[mt], bfr[nt], acc[mt][nt]);
        }
        {
            bf16x8 af[2], bfr[4];
#pragma unroll
            for (int mt = 0; mt < 2; ++mt)
                af[mt] = *(const bf16x8*)&As1[buf][(wm + mt * 16 + l16) * 32 + csw];
#pragma unroll
            for (int nt = 0; nt < 4; ++nt)
                bfr[nt] = *(const bf16x8*)&Bs1[buf][(wn + nt * 16 + l16) * 32 + csw];
#pragma unroll
            for (int mt = 0; mt < 2; ++mt)
#pragma unroll
                for (int nt = 0; nt < 4; ++nt)
                    acc[mt][nt] = MFMA16(af[mt], bfr[nt], acc[mt][nt]);
        }
        __syncthreads();  // publishes prefetched tiles; protects buf reuse
        buf ^= 1;
    }
#pragma unroll
    for (int mt = 0; mt < 2; ++mt)
#pragma unroll
        for (int nt = 0; nt < 4; ++nt)
#pragma unroll
            for (int r = 0; r < 4; ++r) {
                const int row = m0 + wm + mt * 16 + quad * 4 + r;
                const int col = n0 + wn + nt * 16 + l16;
                C[(size_t)row * 1024 + col] = acc[mt][nt][r];
            }
}

// ---------------- launcher ----------------
extern "C" void kernel_launch(void* const* d_in, const int* in_sizes, int n_in,
                              void* d_out, int out_size, void* d_ws, size_t ws_size,
                              hipStream_t stream) {
    const float* x    = (const float*)d_in[0];
    const float* wqkv = (const float*)d_in[3];
    const float* wo   = (const float*)d_in[4];
    const float* qw   = (const float*)d_in[5];
    const float* kw   = (const float*)d_in[6];
    const float* cosb = (const float*)d_in[7];
    const float* sinb = (const float*)d_in[8];

    char* ws = (char*)d_ws;
    // ws (MiB): xb 0-8 | wqkvb 8-14 | wob 14-16 | Qb 16-24 | Kb 24-32
    //           Vt 32-40 | attb 40-48
    if (ws_size < (size_t)48 * 1024 * 1024) return;
    unsigned short* xb    = (unsigned short*)(ws + ((size_t)0 << 20));
    unsigned short* wqkvb = (unsigned short*)(ws + ((size_t)8 << 20));
    unsigned short* wob   = (unsigned short*)(ws + ((size_t)14 << 20));
    unsigned short* Qb    = (unsigned short*)(ws + ((size_t)16 << 20));
    unsigned short* Kb    = (unsigned short*)(ws + ((size_t)24 << 20));
    unsigned short* Vt    = (unsigned short*)(ws + ((size_t)32 << 20));
    unsigned short* attb  = (unsigned short*)(ws + ((size_t)40 << 20));

    // K0: fused converts (one launch)
    cvt3_kernel<<<8192, 256, 0, stream>>>(x, wqkv, wo, xb, wqkvb, wob);

    // K1: qkv GEMM + fused rmsnorm/rope/pack epilogue (128x128x64, 3/CU)
    gemm_qkv<<<dim3(32, 24), 256, 0, stream>>>(xb, wqkvb, cosb, sinb, qw, kw,
                                               Qb, Kb, Vt);

    // K2: sliding-window attention (128-key tiles, K dbuf + early-V, setprio)
    attn_kernel<<<512, 512, 0, stream>>>(Qb, Kb, Vt, attb);

    // K3: y = att @ w_o^T  (M=4096, N=1024, K=1024), fp32 out, BK64 dbuf
    gemm_out<<<dim3(64, 8), 256, 0, stream>>>(attb, wob, (float*)d_out);
}